// Round 7
// baseline (311.305 us; speedup 1.0000x reference)
//
#include <hip/hip_runtime.h>
#include <hip/hip_bf16.h>

using bf16 = __hip_bfloat16;
typedef __attribute__((ext_vector_type(8))) __bf16 bf16x8;
typedef __attribute__((ext_vector_type(4))) float f32x4;

#define GLB_AS(p) ((const __attribute__((address_space(1))) unsigned int*)(p))
#define LDS_AS(p) ((__attribute__((address_space(3))) unsigned int*)(p))

__device__ __forceinline__ void async_copy16(const void* g, void* l) {
  __builtin_amdgcn_global_load_lds(GLB_AS(g), LDS_AS(l), 16, 0, 0);
}

__device__ __forceinline__ f32x4 mfma16x16x32(bf16x8 a, bf16x8 b, f32x4 c) {
  return __builtin_amdgcn_mfma_f32_16x16x32_bf16(a, b, c, 0, 0, 0);
}

__device__ __forceinline__ float bfu2f(unsigned short u) {
  union { unsigned int i; float f; } x;
  x.i = (unsigned int)u << 16;
  return x.f;
}

#define LOG2E 1.44269504f

// ---------------------------------------------------------------------------
// Hx (B,D,T) f32 -> hcat[b][t][0..1023] bf16 (row stride 2048). LDS transpose.
__global__ __launch_bounds__(256) void pack_hx(const float* __restrict__ Hx,
                                               bf16* __restrict__ hcat) {
  __shared__ float tile[64][65];
  const int t0 = blockIdx.x * 64, d0 = blockIdx.y * 64, b = blockIdx.z;
  const int c = threadIdx.x & 63, r0 = threadIdx.x >> 6;
#pragma unroll
  for (int i = 0; i < 16; ++i) {
    const int rd = r0 + i * 4;
    tile[rd][c] = Hx[((size_t)(b * 1024 + d0 + rd)) * 2048 + t0 + c];
  }
  __syncthreads();
#pragma unroll
  for (int i = 0; i < 16; ++i) {
    const int ct = r0 + i * 4;
    hcat[((size_t)(b * 2048 + t0 + ct)) * 2048 + d0 + c] =
        __float2bfloat16(tile[c][ct]);
  }
}

// ---------------------------------------------------------------------------
// One kernel for all f32->bf16 packs + the QKV bias concat (f32 copy).
__global__ __launch_bounds__(256) void pack_all(
    const float* __restrict__ Hf, const float* __restrict__ Wq,
    const float* __restrict__ Wk, const float* __restrict__ Wv,
    const float* __restrict__ Wo, const float* __restrict__ Wg,
    const float* __restrict__ Gm, const float* __restrict__ bq,
    const float* __restrict__ bk, const float* __restrict__ bv,
    bf16* __restrict__ hcat, bf16* __restrict__ Wqkvb, bf16* __restrict__ Wob,
    bf16* __restrict__ Wgb, bf16* __restrict__ Gmb,
    float* __restrict__ qkvbias) {
  const int gid = blockIdx.x * 256 + threadIdx.x;
  const float* src = nullptr;
  bf16* dst = nullptr;
  int lg = 0, ldo = 0, off = 0, idx = 0;
  bool zero = false;
  if (gid < 1048576) { idx = gid; src = Hf; dst = hcat; lg = 8; ldo = 2048; off = 1024; }
  else if (gid < 1572864) { idx = gid - 1048576; src = Wq; dst = Wqkvb; lg = 9; ldo = 2048; }
  else if (gid < 2097152) { idx = gid - 1572864; src = Wk; dst = Wqkvb + (size_t)1024 * 2048; lg = 9; ldo = 2048; }
  else if (gid < 2359296) { idx = gid - 2097152; src = Wv; dst = Wqkvb + (size_t)2048 * 2048; lg = 8; ldo = 2048; }
  else if (gid < 2621440) { idx = gid - 2359296; zero = true; dst = Wqkvb + (size_t)2048 * 2048 + 1024; lg = 8; ldo = 2048; }
  else if (gid < 2883584) { idx = gid - 2621440; src = Wo; dst = Wob; lg = 8; ldo = 1024; }
  else if (gid < 3014656) { idx = gid - 2883584; src = Wg; dst = Wgb; lg = 6; ldo = 256; }
  else if (gid < 3276800) { idx = gid - 3014656; src = Gm; dst = Gmb; lg = 6; ldo = 256; }
  else if (gid < 3277056) { const int i = gid - 3276800; ((float4*)qkvbias)[i] = ((const float4*)bq)[i]; return; }
  else if (gid < 3277312) { const int i = gid - 3277056; ((float4*)(qkvbias + 1024))[i] = ((const float4*)bk)[i]; return; }
  else { const int i = gid - 3277312; ((float4*)(qkvbias + 2048))[i] = ((const float4*)bv)[i]; return; }
  const int row = idx >> lg, c = idx & ((1 << lg) - 1);
  bf16* o = dst + (size_t)row * ldo + off + c * 4;
  __align__(8) bf16 tmp[4];
  if (zero) {
    tmp[0] = tmp[1] = tmp[2] = tmp[3] = __float2bfloat16(0.f);
  } else {
    const float4 v = ((const float4*)src)[(size_t)idx];
    tmp[0] = __float2bfloat16(v.x); tmp[1] = __float2bfloat16(v.y);
    tmp[2] = __float2bfloat16(v.z); tmp[3] = __float2bfloat16(v.w);
  }
  *(ushort4*)o = *(const ushort4*)tmp;
}

// ---------------------------------------------------------------------------
// Combined QKV + bias GEMM, 256x256 tile, BK=64, 8-phase counted-vmcnt
// schedule (T3+T4) + setprio (T5), chunk-XOR swizzle (T2) kept on both sides.
__global__ __launch_bounds__(512, 2) void gemm_qkv_bias(
    const bf16* __restrict__ hcat, const bf16* __restrict__ Wqkv,
    const float* __restrict__ qkvbias, const bf16* __restrict__ Gmb,
    const bf16* __restrict__ Wgb, const float* __restrict__ bg,
    bf16* __restrict__ QKb, bf16* __restrict__ Vt, bf16* __restrict__ biasS) {
  __shared__ __align__(16) bf16 AS[2][256][64];  // 64 KB (even/odd K-tile)
  __shared__ __align__(16) bf16 BS[2][256][64];  // 64 KB
  const int lin = blockIdx.x;
  const bool isqkv = lin < 192;
  int m0, n0, Kd, KT, nit2;
  const bf16 *Ag, *Bg;
  const float* biasv;
  if (isqkv) {
    const int xcd = lin & 7, kk = lin >> 3;  // 24 tiles per XCD: 4m x 6n
    const int mloc = kk / 6, nloc = kk - mloc * 6;
    m0 = ((xcd >> 1) * 4 + mloc) * 256;
    n0 = ((xcd & 1) * 6 + nloc) * 256;
    Ag = hcat; Bg = Wqkv; biasv = qkvbias;
    Kd = 2048; KT = 32; nit2 = 16;
  } else {
    const int l2 = lin - 192;
    m0 = (l2 >> 3) * 256;
    n0 = (l2 & 7) * 256;
    Ag = Gmb; Bg = Wgb; biasv = bg;
    Kd = 256; KT = 4; nit2 = 2;
  }
  const int tid = threadIdx.x, lane = tid & 63, w = tid >> 6;
  const int w8 = w * 8, ln3 = lane >> 3, ch = lane & 7;
  const int fr = lane & 15, ck = lane >> 4;
  const int wm64 = (w >> 2) * 64;   // row sub-offset within each 128-half
  const int wn32 = (w & 3) * 32;    // col sub-offset within each 128-half

  f32x4 acc[8][4];
  const f32x4 fzero = {0.f, 0.f, 0.f, 0.f};
#pragma unroll
  for (int i = 0; i < 8; ++i)
#pragma unroll
    for (int j = 0; j < 4; ++j) acc[i][j] = fzero;

  auto stageA = [&](int buf, int mh, int kt) {
    const int k0 = kt * 64;
#pragma unroll
    for (int l = 0; l < 2; ++l) {
      const int rit = mh * 128 + l * 64 + w8 + ln3;  // rit&7 == ln3
      async_copy16(Ag + (size_t)(m0 + rit) * Kd + k0 + ((ch ^ ln3) << 3),
                   (char*)&AS[buf][0][0] + ((mh * 128 + l * 64 + w8) << 7));
    }
  };
  auto stageB = [&](int buf, int nh, int kt) {
    const int k0 = kt * 64;
#pragma unroll
    for (int l = 0; l < 2; ++l) {
      const int rit = nh * 128 + l * 64 + w8 + ln3;
      async_copy16(Bg + (size_t)(n0 + rit) * Kd + k0 + ((ch ^ ln3) << 3),
                   (char*)&BS[buf][0][0] + ((nh * 128 + l * 64 + w8) << 7));
    }
  };

  bf16x8 af[4][2], bA[2][2], bB[2][2];
  auto ldA = [&](int buf, int mh) {
#pragma unroll
    for (int i = 0; i < 4; ++i)
#pragma unroll
      for (int ks = 0; ks < 2; ++ks)
        af[i][ks] = *(const bf16x8*)(
            &AS[buf][mh * 128 + wm64 + i * 16 + fr][0] +
            (((ks * 4 + ck) ^ (fr & 7)) << 3));
  };
  auto ldB = [&](bf16x8 (&dst)[2][2], int buf, int nh) {
#pragma unroll
    for (int j = 0; j < 2; ++j)
#pragma unroll
      for (int ks = 0; ks < 2; ++ks)
        dst[j][ks] = *(const bf16x8*)(
            &BS[buf][nh * 128 + wn32 + j * 16 + fr][0] +
            (((ks * 4 + ck) ^ (fr & 7)) << 3));
  };

#define BAR() __builtin_amdgcn_s_barrier()
#define LGKM0() asm volatile("s_waitcnt lgkmcnt(0)" ::: "memory")
#define MMAQ(MH, NH, BF)                                                      \
  __builtin_amdgcn_s_setprio(1);                                              \
  _Pragma("unroll") for (int i_ = 0; i_ < 4; ++i_) {                          \
    _Pragma("unroll") for (int j_ = 0; j_ < 2; ++j_) {                        \
      acc[(MH) * 4 + i_][(NH) * 2 + j_] = mfma16x16x32(                       \
          af[i_][0], BF[j_][0], acc[(MH) * 4 + i_][(NH) * 2 + j_]);           \
      acc[(MH) * 4 + i_][(NH) * 2 + j_] = mfma16x16x32(                       \
          af[i_][1], BF[j_][1], acc[(MH) * 4 + i_][(NH) * 2 + j_]);           \
    }                                                                         \
  }                                                                           \
  __builtin_amdgcn_s_setprio(0);

  stageA(0, 0, 0); stageB(0, 0, 0); stageB(0, 1, 0); stageA(0, 1, 0);
  stageA(1, 0, 1); stageB(1, 0, 1);
  asm volatile("s_waitcnt vmcnt(4)" ::: "memory");
  BAR();

  for (int it = 0; it < nit2; ++it) {
    const int kodd = 2 * it + 1;                          // buf1, this iter
    const int kn0 = (2 * it + 2 < KT) ? 2 * it + 2 : KT - 1;  // buf0 next
    const int kn1 = (2 * it + 3 < KT) ? 2 * it + 3 : KT - 1;  // buf1 next

    // -- phase 1: quad (mh0,nh0) of buf0
    ldA(0, 0); ldB(bA, 0, 0);
    stageB(1, 1, kodd);
    asm volatile("s_waitcnt lgkmcnt(8)");
    BAR(); LGKM0();
    MMAQ(0, 0, bA);
    BAR();
    // -- phase 2: (mh0,nh1) buf0
    ldB(bB, 0, 1);
    stageA(1, 1, kodd);
    BAR(); LGKM0();
    MMAQ(0, 1, bB);
    BAR();
    // -- phase 3: (mh1,nh0) buf0
    ldA(0, 1);
    stageA(0, 0, kn0);
    BAR(); LGKM0();
    MMAQ(1, 0, bA);
    BAR();
    // -- phase 4: (mh1,nh1) buf0; counted wait covers phases 5-8 reads
    stageB(0, 0, kn0);
    asm volatile("s_waitcnt vmcnt(4)" ::: "memory");
    BAR();
    MMAQ(1, 1, bB);
    BAR();
    // -- phase 5: (mh0,nh0) buf1
    ldA(1, 0); ldB(bA, 1, 0);
    stageB(0, 1, kn0);
    asm volatile("s_waitcnt lgkmcnt(8)");
    BAR(); LGKM0();
    MMAQ(0, 0, bA);
    BAR();
    // -- phase 6: (mh0,nh1) buf1
    ldB(bB, 1, 1);
    stageA(0, 1, kn0);
    BAR(); LGKM0();
    MMAQ(0, 1, bB);
    BAR();
    // -- phase 7: (mh1,nh0) buf1
    ldA(1, 1);
    stageA(1, 0, kn1);
    BAR(); LGKM0();
    MMAQ(1, 0, bA);
    BAR();
    // -- phase 8: (mh1,nh1) buf1; counted wait covers next iter phases 1-4
    stageB(1, 0, kn1);
    asm volatile("s_waitcnt vmcnt(4)" ::: "memory");
    BAR();
    MMAQ(1, 1, bB);
    BAR();
  }
  asm volatile("s_waitcnt vmcnt(0)" ::: "memory");

  const int erow = (lane >> 4) * 4, ecol = lane & 15;
  if (!isqkv) {
#pragma unroll
    for (int ai = 0; ai < 8; ++ai) {
      const int gm0 = m0 + (ai >> 2) * 128 + wm64 + (ai & 3) * 16 + erow;
#pragma unroll
      for (int bj = 0; bj < 4; ++bj) {
        const int gn = n0 + (bj >> 1) * 128 + wn32 + (bj & 1) * 16 + ecol;
        const float bv = biasv[gn];
#pragma unroll
        for (int r = 0; r < 4; ++r)
          biasS[(size_t)(gm0 + r) * 2048 + gn] =
              __float2bfloat16((acc[ai][bj][r] + bv) * LOG2E);
      }
    }
  } else if (n0 < 2048) {
    const float sc = (n0 < 1024) ? 0.125f * LOG2E : 1.0f;
#pragma unroll
    for (int ai = 0; ai < 8; ++ai) {
      const int gm0 = m0 + (ai >> 2) * 128 + wm64 + (ai & 3) * 16 + erow;
#pragma unroll
      for (int bj = 0; bj < 4; ++bj) {
        const int gn = n0 + (bj >> 1) * 128 + wn32 + (bj & 1) * 16 + ecol;
        const float bv = biasv[gn];
#pragma unroll
        for (int r = 0; r < 4; ++r)
          QKb[(size_t)(gm0 + r) * 2048 + gn] =
              __float2bfloat16((acc[ai][bj][r] + bv) * sc);
      }
    }
  } else {
#pragma unroll
    for (int ai = 0; ai < 8; ++ai) {
      const int gm0 = m0 + (ai >> 2) * 128 + wm64 + (ai & 3) * 16 + erow;
      const int bb = gm0 >> 11;
      const int t = gm0 & 2047;
#pragma unroll
      for (int bj = 0; bj < 4; ++bj) {
        const int gn = n0 + (bj >> 1) * 128 + wn32 + (bj & 1) * 16 + ecol;
        const float bv = biasv[gn];
        const int d = gn - 2048;
        __align__(8) bf16 tmp[4];
#pragma unroll
        for (int r = 0; r < 4; ++r)
          tmp[r] = __float2bfloat16(acc[ai][bj][r] + bv);
        *(ushort4*)(Vt + ((size_t)(bb * 1024 + d)) * 2048 + t) =
            *(const ushort4*)tmp;
      }
    }
  }
#undef MMAQ
#undef LGKM0
#undef BAR
}

// ---------------------------------------------------------------------------
// Out projection: C(4096x1024) f32 = A(4096x1024)@(1024x1024)^T + bo.
__global__ __launch_bounds__(256) void gemm_out(const bf16* __restrict__ A,
                                                const bf16* __restrict__ W,
                                                const float* __restrict__ biasv,
                                                float* __restrict__ C) {
  __shared__ __align__(16) bf16 As[2][128 * 64];  // 2 x 16 KB
  __shared__ __align__(16) bf16 Bs[2][64 * 64];   // 2 x 8 KB
  const int lin = blockIdx.x;
  const int xcd = lin & 7;
  const int kk = lin >> 3;  // 0..63
  const int m0 = (kk >> 1) * 128;
  const int n0 = (xcd * 2 + (kk & 1)) * 64;
  const int tid = threadIdx.x, lane = tid & 63, w = tid >> 6;
  const int wm = (w >> 1) * 64, wn = (w & 1) * 32;
  const int fr = lane & 15;
  const int ck = lane >> 4;

  f32x4 acc[4][2];
  const f32x4 fzero = {0.f, 0.f, 0.f, 0.f};
#pragma unroll
  for (int i = 0; i < 4; ++i)
#pragma unroll
    for (int j = 0; j < 2; ++j) acc[i][j] = fzero;

  auto stage = [&](int it, int buf) {
    const int k0 = it * 64;
#pragma unroll
    for (int is = 0; is < 4; ++is) {
      const int off = is * 4096 + w * 1024;
      const int row = (off >> 7) + (lane >> 3);
      const int sch = ((lane & 7) ^ (row & 7)) * 8;
      async_copy16(A + (size_t)(m0 + row) * 1024 + k0 + sch,
                   (char*)As[buf] + off);
      if (is < 2)
        async_copy16(W + (size_t)(n0 + row) * 1024 + k0 + sch,
                     (char*)Bs[buf] + off);
    }
  };

  stage(0, 0);
  __syncthreads();
  for (int it = 0; it < 16; ++it) {
    const int cur = it & 1;
    if (it + 1 < 16) stage(it + 1, cur ^ 1);
#pragma unroll
    for (int ks = 0; ks < 2; ++ks) {
      bf16x8 af[4], bfr[2];
      const int swk0 = (((ks * 4 + ck) ^ (fr & 7))) * 8;
#pragma unroll
      for (int i = 0; i < 4; ++i)
        af[i] = *(const bf16x8*)(As[cur] + (wm + i * 16 + fr) * 64 + swk0);
#pragma unroll
      for (int j = 0; j < 2; ++j)
        bfr[j] = *(const bf16x8*)(Bs[cur] + (wn + j * 16 + fr) * 64 + swk0);
#pragma unroll
      for (int i = 0; i < 4; ++i)
#pragma unroll
        for (int j = 0; j < 2; ++j)
          acc[i][j] = mfma16x16x32(af[i], bfr[j], acc[i][j]);
    }
    __syncthreads();
  }
  const int erow = (lane >> 4) * 4;
  const int ecol = lane & 15;
#pragma unroll
  for (int i = 0; i < 4; ++i) {
    const int gm0 = m0 + wm + i * 16 + erow;
#pragma unroll
    for (int j = 0; j < 2; ++j) {
      const int gn = n0 + wn + j * 16 + ecol;
      const float bv = biasv[gn];
#pragma unroll
      for (int r = 0; r < 4; ++r)
        C[(size_t)(gm0 + r) * 1024 + gn] = acc[i][j][r] + bv;
    }
  }
}

// ---------------------------------------------------------------------------
// Flash attention, S^T formulation, no-max softmax, key-split. ONE head per
// block, 512 threads = 8 waves x 32 q-rows = 256 q-rows, grid 512 = 2
// blocks/CU (16 waves/CU). LDS = 64 KB: Ks[2]+Vs[2] 32 KB (j-dbuf) + Ps
// 32 KB (stride-64 XOR chunk-swizzled P^T). Per iter: issue K(j+1)+V(j+1)+
// bias(j+1) (10 vmem/thread), vmcnt(10) waits only the PREVIOUS iter's 10,
// one barrier, QK/exp/PV, barrier. Bias regs dbuf.
// launch_bounds (512,2): R6's (512,4) forced a 64-VGPR cap -> scratch spill
// (WRITE_SIZE +17MB, 94us). (512,2) allows ~128 like gemm_qkv_bias (124).
__global__ __launch_bounds__(512, 2) void flash_attn(
    const bf16* __restrict__ Qm, const bf16* __restrict__ Km,
    const bf16* __restrict__ Vtm, const bf16* __restrict__ biasS,
    float* __restrict__ Op0, float* __restrict__ Op1,
    float* __restrict__ lpart) {
  __shared__ __align__(16) bf16 Ks[2][64 * 64];   // j-dbuf, 16 KB
  __shared__ __align__(16) bf16 Vs[2][64 * 64];   // j-dbuf, 16 KB
  __shared__ __align__(16) bf16 Ps[8 * 32 * 64];  // per-wave P^T (swz), 32 KB
  const int lin = blockIdx.x;      // 0..511
  const int h = lin >> 5;          // head 0..15
  const int g = lin & 31;          // (qblk,half,b); lin%8 == g%8 -> same XCD
  const int qblk = g >> 2;         // 0..7
  const int half = (g >> 1) & 1;
  const int b = g & 1;
  const int q0 = qblk * 256;       // 256 q rows per block
  const int tid = threadIdx.x, lane = tid & 63, w = tid >> 6;  // w 0..7
  const int ql = lane & 15, qk = lane >> 4;
  const int T = 2048, D = 1024;
  const int sw0 = (qk ^ (ql & 7)) * 8;
  const int sw1 = ((qk + 4) ^ (ql & 7)) * 8;
  const int ln3 = lane >> 3;
  const int sch = ((lane & 7) ^ ln3) << 3;  // staging chunk swizzle (elems)
  const int jb = half * 16;
  const int qla7 = ql & 7;

  // Q B-frags: B[n=q][k=d], 2 q-subtiles x 2 k-steps
  bf16x8 qf[2][2];  // [qt][ks]
#pragma unroll
  for (int qt = 0; qt < 2; ++qt)
#pragma unroll
    for (int ks = 0; ks < 2; ++ks)
      qf[qt][ks] = *(const bf16x8*)(
          Qm + (size_t)(b * T + q0 + w * 32 + qt * 16 + ql) * 2048 + h * 64 +
          ks * 32 + qk * 8);

  f32x4 acc[4][2];  // [dt][qt]
  const f32x4 fzero = {0.f, 0.f, 0.f, 0.f};
#pragma unroll
  for (int dt = 0; dt < 4; ++dt)
#pragma unroll
    for (int qt = 0; qt < 2; ++qt) acc[dt][qt] = fzero;
  float lp[2] = {0.f, 0.f};

  const bf16* kbase = Km + (size_t)(b * T) * 2048 + h * 64;
  const bf16* vbase = Vtm + (size_t)(b * D + h * 64) * 2048;
  const bf16* bb0 = biasS + (size_t)(b * T + q0 + w * 32 + ql) * 2048 + qk * 4;
  bf16* pb = Ps + w * 2048;
  const int srow = w * 8 + ln3;  // staging row (srow&7 == ln3)

  ushort4 bqA[2][4], bqB[2][4];

// Stage K(jj)+V(jj) into buffer BUF: 2 async/thread. Wave w covers rows
// w*8..w*8+7 (dest = wave-uniform base + lane*16).
#define STAGEKV(BUF, JJ)                                                       \
  {                                                                            \
    async_copy16(kbase + (size_t)((JJ) * 64 + srow) * 2048 + sch,              \
                 (char*)Ks[BUF] + w * 1024);                                   \
    async_copy16(vbase + (size_t)srow * 2048 + (JJ) * 64 + sch,                \
                 (char*)Vs[BUF] + w * 1024);                                   \
  }

  // Prologue: tile j=jb into buf0 + its bias into bqA (10 vmem).
  STAGEKV(0, jb)
#pragma unroll
  for (int qt = 0; qt < 2; ++qt)
#pragma unroll
    for (int jt = 0; jt < 4; ++jt)
      bqA[qt][jt] =
          *(const ushort4*)(bb0 + (size_t)qt * 16 * 2048 + jb * 64 + jt * 16);

// QK^T + bias + exp -> Ps (per-wave, XOR-swizzled stride 64).
#define QKHEAD(CUR, BQC)                                                       \
  {                                                                            \
    const bf16* ksp_ = Ks[CUR];                                                \
    _Pragma("unroll") for (int jt_ = 0; jt_ < 4; ++jt_) {                      \
      const bf16x8 kf0_ = *(const bf16x8*)(ksp_ + (jt_ * 16 + ql) * 64 + sw0); \
      const bf16x8 kf1_ = *(const bf16x8*)(ksp_ + (jt_ * 16 + ql) * 64 + sw1); \
      const int pch_ = (((jt_ * 2 + (qk >> 1)) ^ qla7) << 3) + ((qk & 1) << 2);\
      _Pragma("unroll") for (int qt_ = 0; qt_ < 2; ++qt_) {                    \
        f32x4 c_;                                                              \
        c_[0] = bfu2f(BQC[qt_][jt_].x); c_[1] = bfu2f(BQC[qt_][jt_].y);        \
        c_[2] = bfu2f(BQC[qt_][jt_].z); c_[3] = bfu2f(BQC[qt_][jt_].w);        \
        c_ = mfma16x16x32(kf0_, qf[qt_][0], c_);                               \
        c_ = mfma16x16x32(kf1_, qf[qt_][1], c_);                               \
        __align__(8) bf16 t4_[4];                                              \
        _Pragma("unroll") for (int r_ = 0; r_ < 4; ++r_) {                     \
          const float pv_ = __builtin_amdgcn_exp2f(c_[r_]);                    \
          lp[qt_] += pv_;                                                      \
          t4_[r_] = __float2bfloat16(pv_);                                     \
        }                                                                      \
        *(ushort4*)(pb + (qt_ * 16 + ql) * 64 + pch_) = *(const ushort4*)t4_;  \
      }                                                                        \
    }                                                                          \
  }

// P.V^T accumulate from Vs[CUR] + per-wave Ps (swizzled reads).
#define PVHEAD(CUR)                                                            \
  {                                                                            \
    const bf16* vsp_ = Vs[CUR];                                                \
    __builtin_amdgcn_s_setprio(1);                                             \
    _Pragma("unroll") for (int ks_ = 0; ks_ < 2; ++ks_) {                      \
      const int psw_ = (((ks_ * 4 + qk) ^ qla7) << 3);                         \
      const bf16x8 pf0_ = *(const bf16x8*)(pb + ql * 64 + psw_);               \
      const bf16x8 pf1_ = *(const bf16x8*)(pb + (16 + ql) * 64 + psw_);        \
      const int sw_ = ks_ ? sw1 : sw0;                                         \
      _Pragma("unroll") for (int dt_ = 0; dt_ < 4; ++dt_) {                    \
        const bf16x8 vf_ =                                                     \
            *(const bf16x8*)(vsp_ + (dt_ * 16 + ql) * 64 + sw_);               \
        acc[dt_][0] = mfma16x16x32(pf0_, vf_, acc[dt_][0]);                    \
        acc[dt_][1] = mfma16x16x32(pf1_, vf_, acc[dt_][1]);                    \
      }                                                                        \
    }                                                                          \
    __builtin_amdgcn_s_setprio(0);                                             \
  }

// One key-iteration: stage tile j+1 into CUR^1 + bias(j+1) into BQN (10 vmem),
// vmcnt(10) = drain PREVIOUS iter's 10 (tile CUR ready), barrier, compute,
// barrier. Tail restages j=15 (dead, keeps the count invariant).
#define AITER(JV, CUR, BQC, BQN)                                               \
  {                                                                            \
    const int jn_ = (JV) < 15 ? (JV) + 1 : 15;                                 \
    const int jjn_ = jb + jn_;                                                 \
    STAGEKV((CUR) ^ 1, jjn_)                                                   \
    _Pragma("unroll") for (int qt_ = 0; qt_ < 2; ++qt_)                        \
        _Pragma("unroll") for (int jt_ = 0; jt_ < 4; ++jt_)                    \
            BQN[qt_][jt_] = *(const ushort4*)(bb0 + (size_t)qt_ * 16 * 2048 +  \
                                              jjn_ * 64 + jt_ * 16);           \
    asm volatile("s_waitcnt vmcnt(10)" ::: "memory");                          \
    __builtin_amdgcn_s_barrier();                                              \
    QKHEAD(CUR, BQC)                                                           \
    PVHEAD(CUR)                                                                \
    __builtin_amdgcn_s_barrier();                                              \
  }

  for (int jp = 0; jp < 8; ++jp) {
    AITER(jp * 2, 0, bqA, bqB)
    AITER(jp * 2 + 1, 1, bqB, bqA)
  }
#undef AITER
#undef QKHEAD
#undef PVHEAD
#undef STAGEKV
  asm volatile("s_waitcnt vmcnt(0)" ::: "memory");

  // l partials: reduce across quads (lane's p-values all share q = ...+ql)
#pragma unroll
  for (int qt = 0; qt < 2; ++qt) {
    lp[qt] += __shfl_xor(lp[qt], 16);
    lp[qt] += __shfl_xor(lp[qt], 32);
  }
  if (qk == 0) {
#pragma unroll
    for (int qt = 0; qt < 2; ++qt)
      lpart[half * 65536 + (b * 16 + h) * 2048 + q0 + w * 32 + qt * 16 + ql] =
          lp[qt];
  }
  float* Op = half ? Op1 : Op0;
#pragma unroll
  for (int qt = 0; qt < 2; ++qt)
#pragma unroll
    for (int r = 0; r < 4; ++r) {
      const size_t orow = (size_t)(b * T + q0 + w * 32 + qt * 16 + qk * 4 + r);
#pragma unroll
      for (int dt = 0; dt < 4; ++dt)
        Op[orow * 1024 + h * 64 + dt * 16 + ql] = acc[dt][qt][r];
    }
}

// ---------------------------------------------------------------------------
// Combine key-half partials: AOut = bf16((O0+O1) / (l0+l1)). grid 4096 x 256.
__global__ __launch_bounds__(256) void combine(const float* __restrict__ O0,
                                               const float* __restrict__ O1,
                                               const float* __restrict__ lpart,
                                               bf16* __restrict__ AOut) {
  const int idx = blockIdx.x * 256 + threadIdx.x;  // 0..1048575
  const int row = idx >> 8;
  const int col = (idx & 255) * 4;
  const int b = row >> 11, q = row & 2047, h = col >> 6;
  const int li = (b * 16 + h) * 2048 + q;
  const float inv = __builtin_amdgcn_rcpf(lpart[li] + lpart[65536 + li]);
  const float4 a = *(const float4*)(O0 + (size_t)row * 1024 + col);
  const float4 c = *(const float4*)(O1 + (size_t)row * 1024 + col);
  __align__(8) bf16 t[4] = {
      __float2bfloat16((a.x + c.x) * inv), __float2bfloat16((a.y + c.y) * inv),
      __float2bfloat16((a.z + c.z) * inv), __float2bfloat16((a.w + c.w) * inv)};
  *(ushort4*)(AOut + (size_t)row * 1024 + col) = *(const ushort4*)t;
}

// ---------------------------------------------------------------------------
extern "C" void kernel_launch(void* const* d_in, const int* in_sizes, int n_in,
                              void* d_out, int out_size, void* d_ws,
                              size_t ws_size, hipStream_t stream) {
  (void)in_sizes; (void)n_in; (void)out_size; (void)ws_size;
  const float* Hx = (const float*)d_in[0];
  const float* Hf = (const float*)d_in[1];
  const float* Gm = (const float*)d_in[2];
  const float* Wg = (const float*)d_in[3];
  const float* bg = (const float*)d_in[4];
  const float* Wq = (const float*)d_in[5];
  const float* bq = (const float*)d_in[6];
  const float* Wk = (const float*)d_in[7];
  const float* bk = (const float*)d_in[8];
  const float* Wv = (const float*)d_in[9];
  const float* bv = (const float*)d_in[10];
  const float* Wo = (const float*)d_in[11];
  const float* bo = (const float*)d_in[12];
  float* out = (float*)d_out;

  char* p = (char*)d_ws;
  bf16* hcat = (bf16*)p;   p += (size_t)4096 * 2048 * 2;  // (B*T, 2D)
  bf16* QKb = (bf16*)p;    p += (size_t)4096 * 2048 * 2;  // (B*T, Q|K)
  bf16* Vtb = (bf16*)p;    p += (size_t)4096 * 1024 * 2;  // (B, D, T)
  bf16* biasS = (bf16*)p;  p += (size_t)4096 * 2048 * 2;  // (B*T, T) * log2e
  bf16* AOut = (bf16*)p;   p += (size_t)4096 * 1024 * 2;
  bf16* Wqkvb = (bf16*)p;  p += (size_t)3072 * 2048 * 2;  // (3N, K) packed
  bf16* Wob = (bf16*)p;    p += (size_t)1024 * 1024 * 2;
  bf16* Wgb = (bf16*)p;    p += (size_t)2048 * 256 * 2;
  bf16* Gmb = (bf16*)p;    p += (size_t)4096 * 256 * 2;
  float* qkvbias = (float*)p; p += (size_t)3072 * 4;
  float* Op1 = (float*)p;  p += (size_t)4096 * 1024 * 4;  // key-half-1 partial
  float* lpart = (float*)p; p += (size_t)2 * 65536 * 4;   // l partials
  float* Op0 = (float*)hcat;  // hcat is dead after gemm_qkv_bias; 16.8 MB fits

  pack_hx<<<dim3(32, 16, 2), 256, 0, stream>>>(Hx, hcat);
  pack_all<<<dim3(12803), 256, 0, stream>>>(Hf, Wq, Wk, Wv, Wo, Wg, Gm, bq, bk,
                                            bv, hcat, Wqkvb, Wob, Wgb, Gmb,
                                            qkvbias);
  // QKV projection + attention-bias GEMM, 256^2 8-phase, one dispatch
  gemm_qkv_bias<<<dim3(320), 512, 0, stream>>>(hcat, Wqkvb, qkvbias, Gmb,
                                               Wgb, bg, QKb, Vtb, biasS);
  // fused attention: 1 head/block, 64 KB LDS -> 2 blocks/CU (16 waves/CU)
  flash_attn<<<dim3(512), 512, 0, stream>>>(QKb, QKb + 1024, Vtb, biasS,
                                            Op0, Op1, lpart);
  // combine partials -> AOut bf16
  combine<<<dim3(4096), 256, 0, stream>>>(Op0, Op1, lpart, AOut);
  // output projection (fp32 out), XCD-swizzled
  gemm_out<<<dim3(512), 256, 0, stream>>>(AOut, Wob, bo, out);
}

// Round 8
// 304.610 us; speedup vs baseline: 1.0220x; 1.0220x over previous
//
#include <hip/hip_runtime.h>
#include <hip/hip_bf16.h>

using bf16 = __hip_bfloat16;
typedef __attribute__((ext_vector_type(8))) __bf16 bf16x8;
typedef __attribute__((ext_vector_type(4))) float f32x4;

#define GLB_AS(p) ((const __attribute__((address_space(1))) unsigned int*)(p))
#define LDS_AS(p) ((__attribute__((address_space(3))) unsigned int*)(p))

__device__ __forceinline__ void async_copy16(const void* g, void* l) {
  __builtin_amdgcn_global_load_lds(GLB_AS(g), LDS_AS(l), 16, 0, 0);
}

__device__ __forceinline__ f32x4 mfma16x16x32(bf16x8 a, bf16x8 b, f32x4 c) {
  return __builtin_amdgcn_mfma_f32_16x16x32_bf16(a, b, c, 0, 0, 0);
}

__device__ __forceinline__ float bfu2f(unsigned short u) {
  union { unsigned int i; float f; } x;
  x.i = (unsigned int)u << 16;
  return x.f;
}

#define LOG2E 1.44269504f

// ---------------------------------------------------------------------------
// Hx (B,D,T) f32 -> hcat[b][t][0..1023] bf16 (row stride 2048). LDS transpose.
__global__ __launch_bounds__(256) void pack_hx(const float* __restrict__ Hx,
                                               bf16* __restrict__ hcat) {
  __shared__ float tile[64][65];
  const int t0 = blockIdx.x * 64, d0 = blockIdx.y * 64, b = blockIdx.z;
  const int c = threadIdx.x & 63, r0 = threadIdx.x >> 6;
#pragma unroll
  for (int i = 0; i < 16; ++i) {
    const int rd = r0 + i * 4;
    tile[rd][c] = Hx[((size_t)(b * 1024 + d0 + rd)) * 2048 + t0 + c];
  }
  __syncthreads();
#pragma unroll
  for (int i = 0; i < 16; ++i) {
    const int ct = r0 + i * 4;
    hcat[((size_t)(b * 2048 + t0 + ct)) * 2048 + d0 + c] =
        __float2bfloat16(tile[c][ct]);
  }
}

// ---------------------------------------------------------------------------
// One kernel for all f32->bf16 packs + the QKV bias concat (f32 copy).
__global__ __launch_bounds__(256) void pack_all(
    const float* __restrict__ Hf, const float* __restrict__ Wq,
    const float* __restrict__ Wk, const float* __restrict__ Wv,
    const float* __restrict__ Wo, const float* __restrict__ Wg,
    const float* __restrict__ Gm, const float* __restrict__ bq,
    const float* __restrict__ bk, const float* __restrict__ bv,
    bf16* __restrict__ hcat, bf16* __restrict__ Wqkvb, bf16* __restrict__ Wob,
    bf16* __restrict__ Wgb, bf16* __restrict__ Gmb,
    float* __restrict__ qkvbias) {
  const int gid = blockIdx.x * 256 + threadIdx.x;
  const float* src = nullptr;
  bf16* dst = nullptr;
  int lg = 0, ldo = 0, off = 0, idx = 0;
  bool zero = false;
  if (gid < 1048576) { idx = gid; src = Hf; dst = hcat; lg = 8; ldo = 2048; off = 1024; }
  else if (gid < 1572864) { idx = gid - 1048576; src = Wq; dst = Wqkvb; lg = 9; ldo = 2048; }
  else if (gid < 2097152) { idx = gid - 1572864; src = Wk; dst = Wqkvb + (size_t)1024 * 2048; lg = 9; ldo = 2048; }
  else if (gid < 2359296) { idx = gid - 2097152; src = Wv; dst = Wqkvb + (size_t)2048 * 2048; lg = 8; ldo = 2048; }
  else if (gid < 2621440) { idx = gid - 2359296; zero = true; dst = Wqkvb + (size_t)2048 * 2048 + 1024; lg = 8; ldo = 2048; }
  else if (gid < 2883584) { idx = gid - 2621440; src = Wo; dst = Wob; lg = 8; ldo = 1024; }
  else if (gid < 3014656) { idx = gid - 2883584; src = Wg; dst = Wgb; lg = 6; ldo = 256; }
  else if (gid < 3276800) { idx = gid - 3014656; src = Gm; dst = Gmb; lg = 6; ldo = 256; }
  else if (gid < 3277056) { const int i = gid - 3276800; ((float4*)qkvbias)[i] = ((const float4*)bq)[i]; return; }
  else if (gid < 3277312) { const int i = gid - 3277056; ((float4*)(qkvbias + 1024))[i] = ((const float4*)bk)[i]; return; }
  else { const int i = gid - 3277312; ((float4*)(qkvbias + 2048))[i] = ((const float4*)bv)[i]; return; }
  const int row = idx >> lg, c = idx & ((1 << lg) - 1);
  bf16* o = dst + (size_t)row * ldo + off + c * 4;
  __align__(8) bf16 tmp[4];
  if (zero) {
    tmp[0] = tmp[1] = tmp[2] = tmp[3] = __float2bfloat16(0.f);
  } else {
    const float4 v = ((const float4*)src)[(size_t)idx];
    tmp[0] = __float2bfloat16(v.x); tmp[1] = __float2bfloat16(v.y);
    tmp[2] = __float2bfloat16(v.z); tmp[3] = __float2bfloat16(v.w);
  }
  *(ushort4*)o = *(const ushort4*)tmp;
}

// ---------------------------------------------------------------------------
// Combined QKV + bias GEMM, 256x256 tile, BK=64, 8-phase counted-vmcnt
// schedule (T3+T4) + setprio (T5), chunk-XOR swizzle (T2) kept on both sides.
__global__ __launch_bounds__(512, 2) void gemm_qkv_bias(
    const bf16* __restrict__ hcat, const bf16* __restrict__ Wqkv,
    const float* __restrict__ qkvbias, const bf16* __restrict__ Gmb,
    const bf16* __restrict__ Wgb, const float* __restrict__ bg,
    bf16* __restrict__ QKb, bf16* __restrict__ Vt, bf16* __restrict__ biasS) {
  __shared__ __align__(16) bf16 AS[2][256][64];  // 64 KB (even/odd K-tile)
  __shared__ __align__(16) bf16 BS[2][256][64];  // 64 KB
  const int lin = blockIdx.x;
  const bool isqkv = lin < 192;
  int m0, n0, Kd, KT, nit2;
  const bf16 *Ag, *Bg;
  const float* biasv;
  if (isqkv) {
    const int xcd = lin & 7, kk = lin >> 3;  // 24 tiles per XCD: 4m x 6n
    const int mloc = kk / 6, nloc = kk - mloc * 6;
    m0 = ((xcd >> 1) * 4 + mloc) * 256;
    n0 = ((xcd & 1) * 6 + nloc) * 256;
    Ag = hcat; Bg = Wqkv; biasv = qkvbias;
    Kd = 2048; KT = 32; nit2 = 16;
  } else {
    const int l2 = lin - 192;
    m0 = (l2 >> 3) * 256;
    n0 = (l2 & 7) * 256;
    Ag = Gmb; Bg = Wgb; biasv = bg;
    Kd = 256; KT = 4; nit2 = 2;
  }
  const int tid = threadIdx.x, lane = tid & 63, w = tid >> 6;
  const int w8 = w * 8, ln3 = lane >> 3, ch = lane & 7;
  const int fr = lane & 15, ck = lane >> 4;
  const int wm64 = (w >> 2) * 64;   // row sub-offset within each 128-half
  const int wn32 = (w & 3) * 32;    // col sub-offset within each 128-half

  f32x4 acc[8][4];
  const f32x4 fzero = {0.f, 0.f, 0.f, 0.f};
#pragma unroll
  for (int i = 0; i < 8; ++i)
#pragma unroll
    for (int j = 0; j < 4; ++j) acc[i][j] = fzero;

  auto stageA = [&](int buf, int mh, int kt) {
    const int k0 = kt * 64;
#pragma unroll
    for (int l = 0; l < 2; ++l) {
      const int rit = mh * 128 + l * 64 + w8 + ln3;  // rit&7 == ln3
      async_copy16(Ag + (size_t)(m0 + rit) * Kd + k0 + ((ch ^ ln3) << 3),
                   (char*)&AS[buf][0][0] + ((mh * 128 + l * 64 + w8) << 7));
    }
  };
  auto stageB = [&](int buf, int nh, int kt) {
    const int k0 = kt * 64;
#pragma unroll
    for (int l = 0; l < 2; ++l) {
      const int rit = nh * 128 + l * 64 + w8 + ln3;
      async_copy16(Bg + (size_t)(n0 + rit) * Kd + k0 + ((ch ^ ln3) << 3),
                   (char*)&BS[buf][0][0] + ((nh * 128 + l * 64 + w8) << 7));
    }
  };

  bf16x8 af[4][2], bA[2][2], bB[2][2];
  auto ldA = [&](int buf, int mh) {
#pragma unroll
    for (int i = 0; i < 4; ++i)
#pragma unroll
      for (int ks = 0; ks < 2; ++ks)
        af[i][ks] = *(const bf16x8*)(
            &AS[buf][mh * 128 + wm64 + i * 16 + fr][0] +
            (((ks * 4 + ck) ^ (fr & 7)) << 3));
  };
  auto ldB = [&](bf16x8 (&dst)[2][2], int buf, int nh) {
#pragma unroll
    for (int j = 0; j < 2; ++j)
#pragma unroll
      for (int ks = 0; ks < 2; ++ks)
        dst[j][ks] = *(const bf16x8*)(
            &BS[buf][nh * 128 + wn32 + j * 16 + fr][0] +
            (((ks * 4 + ck) ^ (fr & 7)) << 3));
  };

#define BAR() __builtin_amdgcn_s_barrier()
#define LGKM0() asm volatile("s_waitcnt lgkmcnt(0)" ::: "memory")
#define MMAQ(MH, NH, BF)                                                      \
  __builtin_amdgcn_s_setprio(1);                                              \
  _Pragma("unroll") for (int i_ = 0; i_ < 4; ++i_) {                          \
    _Pragma("unroll") for (int j_ = 0; j_ < 2; ++j_) {                        \
      acc[(MH) * 4 + i_][(NH) * 2 + j_] = mfma16x16x32(                       \
          af[i_][0], BF[j_][0], acc[(MH) * 4 + i_][(NH) * 2 + j_]);           \
      acc[(MH) * 4 + i_][(NH) * 2 + j_] = mfma16x16x32(                       \
          af[i_][1], BF[j_][1], acc[(MH) * 4 + i_][(NH) * 2 + j_]);           \
    }                                                                         \
  }                                                                           \
  __builtin_amdgcn_s_setprio(0);

  stageA(0, 0, 0); stageB(0, 0, 0); stageB(0, 1, 0); stageA(0, 1, 0);
  stageA(1, 0, 1); stageB(1, 0, 1);
  asm volatile("s_waitcnt vmcnt(4)" ::: "memory");
  BAR();

  for (int it = 0; it < nit2; ++it) {
    const int kodd = 2 * it + 1;                          // buf1, this iter
    const int kn0 = (2 * it + 2 < KT) ? 2 * it + 2 : KT - 1;  // buf0 next
    const int kn1 = (2 * it + 3 < KT) ? 2 * it + 3 : KT - 1;  // buf1 next

    // -- phase 1: quad (mh0,nh0) of buf0
    ldA(0, 0); ldB(bA, 0, 0);
    stageB(1, 1, kodd);
    asm volatile("s_waitcnt lgkmcnt(8)");
    BAR(); LGKM0();
    MMAQ(0, 0, bA);
    BAR();
    // -- phase 2: (mh0,nh1) buf0
    ldB(bB, 0, 1);
    stageA(1, 1, kodd);
    BAR(); LGKM0();
    MMAQ(0, 1, bB);
    BAR();
    // -- phase 3: (mh1,nh0) buf0
    ldA(0, 1);
    stageA(0, 0, kn0);
    BAR(); LGKM0();
    MMAQ(1, 0, bA);
    BAR();
    // -- phase 4: (mh1,nh1) buf0; counted wait covers phases 5-8 reads
    stageB(0, 0, kn0);
    asm volatile("s_waitcnt vmcnt(4)" ::: "memory");
    BAR();
    MMAQ(1, 1, bB);
    BAR();
    // -- phase 5: (mh0,nh0) buf1
    ldA(1, 0); ldB(bA, 1, 0);
    stageB(0, 1, kn0);
    asm volatile("s_waitcnt lgkmcnt(8)");
    BAR(); LGKM0();
    MMAQ(0, 0, bA);
    BAR();
    // -- phase 6: (mh0,nh1) buf1
    ldB(bB, 1, 1);
    stageA(0, 1, kn0);
    BAR(); LGKM0();
    MMAQ(0, 1, bB);
    BAR();
    // -- phase 7: (mh1,nh0) buf1
    ldA(1, 1);
    stageA(1, 0, kn1);
    BAR(); LGKM0();
    MMAQ(1, 0, bA);
    BAR();
    // -- phase 8: (mh1,nh1) buf1; counted wait covers next iter phases 1-4
    stageB(1, 0, kn1);
    asm volatile("s_waitcnt vmcnt(4)" ::: "memory");
    BAR();
    MMAQ(1, 1, bB);
    BAR();
  }
  asm volatile("s_waitcnt vmcnt(0)" ::: "memory");

  const int erow = (lane >> 4) * 4, ecol = lane & 15;
  if (!isqkv) {
#pragma unroll
    for (int ai = 0; ai < 8; ++ai) {
      const int gm0 = m0 + (ai >> 2) * 128 + wm64 + (ai & 3) * 16 + erow;
#pragma unroll
      for (int bj = 0; bj < 4; ++bj) {
        const int gn = n0 + (bj >> 1) * 128 + wn32 + (bj & 1) * 16 + ecol;
        const float bv = biasv[gn];
#pragma unroll
        for (int r = 0; r < 4; ++r)
          biasS[(size_t)(gm0 + r) * 2048 + gn] =
              __float2bfloat16((acc[ai][bj][r] + bv) * LOG2E);
      }
    }
  } else if (n0 < 2048) {
    const float sc = (n0 < 1024) ? 0.125f * LOG2E : 1.0f;
#pragma unroll
    for (int ai = 0; ai < 8; ++ai) {
      const int gm0 = m0 + (ai >> 2) * 128 + wm64 + (ai & 3) * 16 + erow;
#pragma unroll
      for (int bj = 0; bj < 4; ++bj) {
        const int gn = n0 + (bj >> 1) * 128 + wn32 + (bj & 1) * 16 + ecol;
        const float bv = biasv[gn];
#pragma unroll
        for (int r = 0; r < 4; ++r)
          QKb[(size_t)(gm0 + r) * 2048 + gn] =
              __float2bfloat16((acc[ai][bj][r] + bv) * sc);
      }
    }
  } else {
#pragma unroll
    for (int ai = 0; ai < 8; ++ai) {
      const int gm0 = m0 + (ai >> 2) * 128 + wm64 + (ai & 3) * 16 + erow;
      const int bb = gm0 >> 11;
      const int t = gm0 & 2047;
#pragma unroll
      for (int bj = 0; bj < 4; ++bj) {
        const int gn = n0 + (bj >> 1) * 128 + wn32 + (bj & 1) * 16 + ecol;
        const float bv = biasv[gn];
        const int d = gn - 2048;
        __align__(8) bf16 tmp[4];
#pragma unroll
        for (int r = 0; r < 4; ++r)
          tmp[r] = __float2bfloat16(acc[ai][bj][r] + bv);
        *(ushort4*)(Vt + ((size_t)(bb * 1024 + d)) * 2048 + t) =
            *(const ushort4*)tmp;
      }
    }
  }
#undef MMAQ
#undef LGKM0
#undef BAR
}

// ---------------------------------------------------------------------------
// Out projection: C(4096x1024) f32 = A(4096x1024)@(1024x1024)^T + bo.
__global__ __launch_bounds__(256) void gemm_out(const bf16* __restrict__ A,
                                                const bf16* __restrict__ W,
                                                const float* __restrict__ biasv,
                                                float* __restrict__ C) {
  __shared__ __align__(16) bf16 As[2][128 * 64];  // 2 x 16 KB
  __shared__ __align__(16) bf16 Bs[2][64 * 64];   // 2 x 8 KB
  const int lin = blockIdx.x;
  const int xcd = lin & 7;
  const int kk = lin >> 3;  // 0..63
  const int m0 = (kk >> 1) * 128;
  const int n0 = (xcd * 2 + (kk & 1)) * 64;
  const int tid = threadIdx.x, lane = tid & 63, w = tid >> 6;
  const int wm = (w >> 1) * 64, wn = (w & 1) * 32;
  const int fr = lane & 15;
  const int ck = lane >> 4;

  f32x4 acc[4][2];
  const f32x4 fzero = {0.f, 0.f, 0.f, 0.f};
#pragma unroll
  for (int i = 0; i < 4; ++i)
#pragma unroll
    for (int j = 0; j < 2; ++j) acc[i][j] = fzero;

  auto stage = [&](int it, int buf) {
    const int k0 = it * 64;
#pragma unroll
    for (int is = 0; is < 4; ++is) {
      const int off = is * 4096 + w * 1024;
      const int row = (off >> 7) + (lane >> 3);
      const int sch = ((lane & 7) ^ (row & 7)) * 8;
      async_copy16(A + (size_t)(m0 + row) * 1024 + k0 + sch,
                   (char*)As[buf] + off);
      if (is < 2)
        async_copy16(W + (size_t)(n0 + row) * 1024 + k0 + sch,
                     (char*)Bs[buf] + off);
    }
  };

  stage(0, 0);
  __syncthreads();
  for (int it = 0; it < 16; ++it) {
    const int cur = it & 1;
    if (it + 1 < 16) stage(it + 1, cur ^ 1);
#pragma unroll
    for (int ks = 0; ks < 2; ++ks) {
      bf16x8 af[4], bfr[2];
      const int swk0 = (((ks * 4 + ck) ^ (fr & 7))) * 8;
#pragma unroll
      for (int i = 0; i < 4; ++i)
        af[i] = *(const bf16x8*)(As[cur] + (wm + i * 16 + fr) * 64 + swk0);
#pragma unroll
      for (int j = 0; j < 2; ++j)
        bfr[j] = *(const bf16x8*)(Bs[cur] + (wn + j * 16 + fr) * 64 + swk0);
#pragma unroll
      for (int i = 0; i < 4; ++i)
#pragma unroll
        for (int j = 0; j < 2; ++j)
          acc[i][j] = mfma16x16x32(af[i], bfr[j], acc[i][j]);
    }
    __syncthreads();
  }
  const int erow = (lane >> 4) * 4;
  const int ecol = lane & 15;
#pragma unroll
  for (int i = 0; i < 4; ++i) {
    const int gm0 = m0 + wm + i * 16 + erow;
#pragma unroll
    for (int j = 0; j < 2; ++j) {
      const int gn = n0 + wn + j * 16 + ecol;
      const float bv = biasv[gn];
#pragma unroll
      for (int r = 0; r < 4; ++r)
        C[(size_t)(gm0 + r) * 1024 + gn] = acc[i][j][r] + bv;
    }
  }
}

// ---------------------------------------------------------------------------
// Flash attention, S^T formulation, no-max softmax, key-split. R1's PROVEN
// inner loop (2-barrier, single-buffered K/V, stride-72 Ps) with ONE HEAD per
// 256-thread block (4 waves x 32 q-rows = 128 q-rows). Grid 1024 = 16 qblk x
// 2 half x 2 b x 16 h = 4 blocks/CU (R1 was grid-limited at 2). LDS 34 KB:
// 4 x 34 = 136 <= 160 KB -> 4 resident -> 16 waves/CU of INDEPENDENT barrier
// domains (one block's staging drain overlaps three others' compute).
// Plain launch_bounds(256): R6/R7 showed min-wave clamps force VGPR caps
// (64) -> scratch spill. Mapping lin = h*64 + g keeps all 16 heads of one
// (b,qblk,half) on one XCD -> shared bias slice L2-resident.
__global__ __launch_bounds__(256) void flash_attn(
    const bf16* __restrict__ Qm, const bf16* __restrict__ Km,
    const bf16* __restrict__ Vtm, const bf16* __restrict__ biasS,
    float* __restrict__ Op0, float* __restrict__ Op1,
    float* __restrict__ lpart) {
  __shared__ __align__(16) bf16 Ks[64 * 64];      // 8 KB
  __shared__ __align__(16) bf16 Vs[64 * 64];      // 8 KB
  __shared__ __align__(16) bf16 Ps[4 * 32 * 72];  // per-wave P^T, 18 KB
  const int lin = blockIdx.x;      // 0..1023
  const int h = lin >> 6;          // head 0..15
  const int g = lin & 63;          // (qblk,half,b); lin%8 == g%8 -> same XCD
  const int qblk = g >> 2;         // 0..15
  const int half = (g >> 1) & 1;
  const int b = g & 1;
  const int q0 = qblk * 128;       // 128 q rows per block
  const int tid = threadIdx.x, lane = tid & 63, w = tid >> 6;  // w 0..3
  const int ql = lane & 15, qk = lane >> 4;
  const int T = 2048, D = 1024;
  const int sw0 = (qk ^ (ql & 7)) * 8;
  const int sw1 = ((qk + 4) ^ (ql & 7)) * 8;

  // Q B-frags: B[n=q][k=d], 2 q-subtiles x 2 k-steps
  bf16x8 qf[2][2];  // [qt][ks]
#pragma unroll
  for (int qt = 0; qt < 2; ++qt)
#pragma unroll
    for (int ks = 0; ks < 2; ++ks)
      qf[qt][ks] = *(const bf16x8*)(
          Qm + (size_t)(b * T + q0 + w * 32 + qt * 16 + ql) * 2048 + h * 64 +
          ks * 32 + qk * 8);

  f32x4 acc[4][2];  // [dt][qt]
  const f32x4 fzero = {0.f, 0.f, 0.f, 0.f};
#pragma unroll
  for (int dt = 0; dt < 4; ++dt)
#pragma unroll
    for (int qt = 0; qt < 2; ++qt) acc[dt][qt] = fzero;
  float lp[2] = {0.f, 0.f};

  const bf16* kbase = Km + (size_t)(b * T) * 2048 + h * 64;
  const bf16* vbase = Vtm + (size_t)(b * D + h * 64) * 2048;
  const bf16* bb0 = biasS + (size_t)(b * T + q0 + w * 32 + ql) * 2048 + qk * 4;
  bf16* pb = Ps + w * 2304;

  for (int j = 0; j < 16; ++j) {
    const int jj = half * 16 + j;  // global key-block
    __syncthreads();
#pragma unroll
    for (int is = 0; is < 2; ++is) {
      const int off = is * 4096 + w * 1024;
      const int row = (off >> 7) + (lane >> 3);
      const int sch = ((lane & 7) ^ (row & 7)) * 8;
      async_copy16(kbase + (size_t)(jj * 64 + row) * 2048 + sch,
                   (char*)Ks + off);
      async_copy16(vbase + (size_t)row * 2048 + jj * 64 + sch,
                   (char*)Vs + off);
    }
    // bias prefetch (overlaps staging drain)
    ushort4 bq[2][4];
#pragma unroll
    for (int qt = 0; qt < 2; ++qt)
#pragma unroll
      for (int jt = 0; jt < 4; ++jt)
        bq[qt][jt] = *(const ushort4*)(bb0 + (size_t)qt * 16 * 2048 + jj * 64 +
                                       jt * 16);
    __syncthreads();
    // S^T tiles: rows=key, cols=q; bias as MFMA C-init
#pragma unroll
    for (int jt = 0; jt < 4; ++jt) {
      const bf16x8 kf0 = *(const bf16x8*)(Ks + (jt * 16 + ql) * 64 + sw0);
      const bf16x8 kf1 = *(const bf16x8*)(Ks + (jt * 16 + ql) * 64 + sw1);
#pragma unroll
      for (int qt = 0; qt < 2; ++qt) {
        f32x4 c;
        c[0] = bfu2f(bq[qt][jt].x); c[1] = bfu2f(bq[qt][jt].y);
        c[2] = bfu2f(bq[qt][jt].z); c[3] = bfu2f(bq[qt][jt].w);
        c = mfma16x16x32(kf0, qf[qt][0], c);
        c = mfma16x16x32(kf1, qf[qt][1], c);
        __align__(8) bf16 t4[4];
#pragma unroll
        for (int r = 0; r < 4; ++r) {
          const float pv = __builtin_amdgcn_exp2f(c[r]);
          lp[qt] += pv;
          t4[r] = __float2bfloat16(pv);
        }
        *(ushort4*)(pb + (qt * 16 + ql) * 72 + jt * 16 + qk * 4) =
            *(const ushort4*)t4;
      }
    }
    // O[q][d] += P.V^T ; V-frags shared across q-subtiles
    __builtin_amdgcn_s_setprio(1);
#pragma unroll
    for (int ks = 0; ks < 2; ++ks) {
      const bf16x8 pf0 = *(const bf16x8*)(pb + ql * 72 + ks * 32 + qk * 8);
      const bf16x8 pf1 =
          *(const bf16x8*)(pb + (16 + ql) * 72 + ks * 32 + qk * 8);
      const int sw = ks ? sw1 : sw0;
#pragma unroll
      for (int dt = 0; dt < 4; ++dt) {
        const bf16x8 vf = *(const bf16x8*)(Vs + (dt * 16 + ql) * 64 + sw);
        acc[dt][0] = mfma16x16x32(pf0, vf, acc[dt][0]);
        acc[dt][1] = mfma16x16x32(pf1, vf, acc[dt][1]);
      }
    }
    __builtin_amdgcn_s_setprio(0);
  }
  // l partials: reduce across quads (lane's p-values all share q = ...+ql)
#pragma unroll
  for (int qt = 0; qt < 2; ++qt) {
    lp[qt] += __shfl_xor(lp[qt], 16);
    lp[qt] += __shfl_xor(lp[qt], 32);
  }
  if (qk == 0) {
#pragma unroll
    for (int qt = 0; qt < 2; ++qt)
      lpart[half * 65536 + (b * 16 + h) * 2048 + q0 + w * 32 + qt * 16 + ql] =
          lp[qt];
  }
  float* Op = half ? Op1 : Op0;
#pragma unroll
  for (int qt = 0; qt < 2; ++qt)
#pragma unroll
    for (int r = 0; r < 4; ++r) {
      const size_t orow = (size_t)(b * T + q0 + w * 32 + qt * 16 + qk * 4 + r);
#pragma unroll
      for (int dt = 0; dt < 4; ++dt)
        Op[orow * 1024 + h * 64 + dt * 16 + ql] = acc[dt][qt][r];
    }
}

// ---------------------------------------------------------------------------
// Combine key-half partials: AOut = bf16((O0+O1) / (l0+l1)). grid 4096 x 256.
__global__ __launch_bounds__(256) void combine(const float* __restrict__ O0,
                                               const float* __restrict__ O1,
                                               const float* __restrict__ lpart,
                                               bf16* __restrict__ AOut) {
  const int idx = blockIdx.x * 256 + threadIdx.x;  // 0..1048575
  const int row = idx >> 8;
  const int col = (idx & 255) * 4;
  const int b = row >> 11, q = row & 2047, h = col >> 6;
  const int li = (b * 16 + h) * 2048 + q;
  const float inv = __builtin_amdgcn_rcpf(lpart[li] + lpart[65536 + li]);
  const float4 a = *(const float4*)(O0 + (size_t)row * 1024 + col);
  const float4 c = *(const float4*)(O1 + (size_t)row * 1024 + col);
  __align__(8) bf16 t[4] = {
      __float2bfloat16((a.x + c.x) * inv), __float2bfloat16((a.y + c.y) * inv),
      __float2bfloat16((a.z + c.z) * inv), __float2bfloat16((a.w + c.w) * inv)};
  *(ushort4*)(AOut + (size_t)row * 1024 + col) = *(const ushort4*)t;
}

// ---------------------------------------------------------------------------
extern "C" void kernel_launch(void* const* d_in, const int* in_sizes, int n_in,
                              void* d_out, int out_size, void* d_ws,
                              size_t ws_size, hipStream_t stream) {
  (void)in_sizes; (void)n_in; (void)out_size; (void)ws_size;
  const float* Hx = (const float*)d_in[0];
  const float* Hf = (const float*)d_in[1];
  const float* Gm = (const float*)d_in[2];
  const float* Wg = (const float*)d_in[3];
  const float* bg = (const float*)d_in[4];
  const float* Wq = (const float*)d_in[5];
  const float* bq = (const float*)d_in[6];
  const float* Wk = (const float*)d_in[7];
  const float* bk = (const float*)d_in[8];
  const float* Wv = (const float*)d_in[9];
  const float* bv = (const float*)d_in[10];
  const float* Wo = (const float*)d_in[11];
  const float* bo = (const float*)d_in[12];
  float* out = (float*)d_out;

  char* p = (char*)d_ws;
  bf16* hcat = (bf16*)p;   p += (size_t)4096 * 2048 * 2;  // (B*T, 2D)
  bf16* QKb = (bf16*)p;    p += (size_t)4096 * 2048 * 2;  // (B*T, Q|K)
  bf16* Vtb = (bf16*)p;    p += (size_t)4096 * 1024 * 2;  // (B, D, T)
  bf16* biasS = (bf16*)p;  p += (size_t)4096 * 2048 * 2;  // (B*T, T) * log2e
  bf16* AOut = (bf16*)p;   p += (size_t)4096 * 1024 * 2;
  bf16* Wqkvb = (bf16*)p;  p += (size_t)3072 * 2048 * 2;  // (3N, K) packed
  bf16* Wob = (bf16*)p;    p += (size_t)1024 * 1024 * 2;
  bf16* Wgb = (bf16*)p;    p += (size_t)2048 * 256 * 2;
  bf16* Gmb = (bf16*)p;    p += (size_t)4096 * 256 * 2;
  float* qkvbias = (float*)p; p += (size_t)3072 * 4;
  float* Op1 = (float*)p;  p += (size_t)4096 * 1024 * 4;  // key-half-1 partial
  float* lpart = (float*)p; p += (size_t)2 * 65536 * 4;   // l partials
  float* Op0 = (float*)hcat;  // hcat is dead after gemm_qkv_bias; 16.8 MB fits

  pack_hx<<<dim3(32, 16, 2), 256, 0, stream>>>(Hx, hcat);
  pack_all<<<dim3(12803), 256, 0, stream>>>(Hf, Wq, Wk, Wv, Wo, Wg, Gm, bq, bk,
                                            bv, hcat, Wqkvb, Wob, Wgb, Gmb,
                                            qkvbias);
  // QKV projection + attention-bias GEMM, 256^2 8-phase, one dispatch
  gemm_qkv_bias<<<dim3(320), 512, 0, stream>>>(hcat, Wqkvb, qkvbias, Gmb,
                                               Wgb, bg, QKb, Vtb, biasS);
  // fused attention: 1 head / 256-thr block, 34 KB LDS -> 4 blocks/CU
  flash_attn<<<dim3(1024), 256, 0, stream>>>(QKb, QKb + 1024, Vtb, biasS,
                                             Op0, Op1, lpart);
  // combine partials -> AOut bf16
  combine<<<dim3(4096), 256, 0, stream>>>(Op0, Op1, lpart, AOut);
  // output projection (fp32 out), XCD-swizzled
  gemm_out<<<dim3(512), 256, 0, stream>>>(AOut, Wob, bo, out);
}

// Round 9
// 278.188 us; speedup vs baseline: 1.1190x; 1.0950x over previous
//
#include <hip/hip_runtime.h>
#include <hip/hip_bf16.h>

using bf16 = __hip_bfloat16;
typedef __attribute__((ext_vector_type(8))) __bf16 bf16x8;
typedef __attribute__((ext_vector_type(4))) float f32x4;

#define GLB_AS(p) ((const __attribute__((address_space(1))) unsigned int*)(p))
#define LDS_AS(p) ((__attribute__((address_space(3))) unsigned int*)(p))

__device__ __forceinline__ void async_copy16(const void* g, void* l) {
  __builtin_amdgcn_global_load_lds(GLB_AS(g), LDS_AS(l), 16, 0, 0);
}

__device__ __forceinline__ f32x4 mfma16x16x32(bf16x8 a, bf16x8 b, f32x4 c) {
  return __builtin_amdgcn_mfma_f32_16x16x32_bf16(a, b, c, 0, 0, 0);
}

__device__ __forceinline__ float bfu2f(unsigned short u) {
  union { unsigned int i; float f; } x;
  x.i = (unsigned int)u << 16;
  return x.f;
}

#define LOG2E 1.44269504f

// ---------------------------------------------------------------------------
// Hx (B,D,T) f32 -> hcat[b][t][0..1023] bf16 (row stride 2048). LDS transpose.
__global__ __launch_bounds__(256) void pack_hx(const float* __restrict__ Hx,
                                               bf16* __restrict__ hcat) {
  __shared__ float tile[64][65];
  const int t0 = blockIdx.x * 64, d0 = blockIdx.y * 64, b = blockIdx.z;
  const int c = threadIdx.x & 63, r0 = threadIdx.x >> 6;
#pragma unroll
  for (int i = 0; i < 16; ++i) {
    const int rd = r0 + i * 4;
    tile[rd][c] = Hx[((size_t)(b * 1024 + d0 + rd)) * 2048 + t0 + c];
  }
  __syncthreads();
#pragma unroll
  for (int i = 0; i < 16; ++i) {
    const int ct = r0 + i * 4;
    hcat[((size_t)(b * 2048 + t0 + ct)) * 2048 + d0 + c] =
        __float2bfloat16(tile[c][ct]);
  }
}

// ---------------------------------------------------------------------------
// One kernel for all f32->bf16 packs + the QKV bias concat (f32 copy).
__global__ __launch_bounds__(256) void pack_all(
    const float* __restrict__ Hf, const float* __restrict__ Wq,
    const float* __restrict__ Wk, const float* __restrict__ Wv,
    const float* __restrict__ Wo, const float* __restrict__ Wg,
    const float* __restrict__ Gm, const float* __restrict__ bq,
    const float* __restrict__ bk, const float* __restrict__ bv,
    bf16* __restrict__ hcat, bf16* __restrict__ Wqkvb, bf16* __restrict__ Wob,
    bf16* __restrict__ Wgb, bf16* __restrict__ Gmb,
    float* __restrict__ qkvbias) {
  const int gid = blockIdx.x * 256 + threadIdx.x;
  const float* src = nullptr;
  bf16* dst = nullptr;
  int lg = 0, ldo = 0, off = 0, idx = 0;
  bool zero = false;
  if (gid < 1048576) { idx = gid; src = Hf; dst = hcat; lg = 8; ldo = 2048; off = 1024; }
  else if (gid < 1572864) { idx = gid - 1048576; src = Wq; dst = Wqkvb; lg = 9; ldo = 2048; }
  else if (gid < 2097152) { idx = gid - 1572864; src = Wk; dst = Wqkvb + (size_t)1024 * 2048; lg = 9; ldo = 2048; }
  else if (gid < 2359296) { idx = gid - 2097152; src = Wv; dst = Wqkvb + (size_t)2048 * 2048; lg = 8; ldo = 2048; }
  else if (gid < 2621440) { idx = gid - 2359296; zero = true; dst = Wqkvb + (size_t)2048 * 2048 + 1024; lg = 8; ldo = 2048; }
  else if (gid < 2883584) { idx = gid - 2621440; src = Wo; dst = Wob; lg = 8; ldo = 1024; }
  else if (gid < 3014656) { idx = gid - 2883584; src = Wg; dst = Wgb; lg = 6; ldo = 256; }
  else if (gid < 3276800) { idx = gid - 3014656; src = Gm; dst = Gmb; lg = 6; ldo = 256; }
  else if (gid < 3277056) { const int i = gid - 3276800; ((float4*)qkvbias)[i] = ((const float4*)bq)[i]; return; }
  else if (gid < 3277312) { const int i = gid - 3277056; ((float4*)(qkvbias + 1024))[i] = ((const float4*)bk)[i]; return; }
  else { const int i = gid - 3277312; ((float4*)(qkvbias + 2048))[i] = ((const float4*)bv)[i]; return; }
  const int row = idx >> lg, c = idx & ((1 << lg) - 1);
  bf16* o = dst + (size_t)row * ldo + off + c * 4;
  __align__(8) bf16 tmp[4];
  if (zero) {
    tmp[0] = tmp[1] = tmp[2] = tmp[3] = __float2bfloat16(0.f);
  } else {
    const float4 v = ((const float4*)src)[(size_t)idx];
    tmp[0] = __float2bfloat16(v.x); tmp[1] = __float2bfloat16(v.y);
    tmp[2] = __float2bfloat16(v.z); tmp[3] = __float2bfloat16(v.w);
  }
  *(ushort4*)o = *(const ushort4*)tmp;
}

// ---------------------------------------------------------------------------
// Combined QKV + bias GEMM, 256x256 tile, BK=64, 8-phase counted-vmcnt
// schedule (T3+T4) + setprio (T5), chunk-XOR swizzle (T2) kept on both sides.
// 512 threads = 8 waves (2M x 4N, half-aligned quadrants so each phase's
// MFMA reads exactly one staged A-half and one B-half).
// Grid 320 = 192 QKV tiles (XCD-grouped 4m x 6n) + 128 bias tiles.
// LDS 128 KiB -> 1 block/CU.
__global__ __launch_bounds__(512, 2) void gemm_qkv_bias(
    const bf16* __restrict__ hcat, const bf16* __restrict__ Wqkv,
    const float* __restrict__ qkvbias, const bf16* __restrict__ Gmb,
    const bf16* __restrict__ Wgb, const float* __restrict__ bg,
    bf16* __restrict__ QKb, bf16* __restrict__ Vt, bf16* __restrict__ biasS) {
  __shared__ __align__(16) bf16 AS[2][256][64];  // 64 KB (even/odd K-tile)
  __shared__ __align__(16) bf16 BS[2][256][64];  // 64 KB
  const int lin = blockIdx.x;
  const bool isqkv = lin < 192;
  int m0, n0, Kd, KT, nit2;
  const bf16 *Ag, *Bg;
  const float* biasv;
  if (isqkv) {
    const int xcd = lin & 7, kk = lin >> 3;  // 24 tiles per XCD: 4m x 6n
    const int mloc = kk / 6, nloc = kk - mloc * 6;
    m0 = ((xcd >> 1) * 4 + mloc) * 256;
    n0 = ((xcd & 1) * 6 + nloc) * 256;
    Ag = hcat; Bg = Wqkv; biasv = qkvbias;
    Kd = 2048; KT = 32; nit2 = 16;
  } else {
    const int l2 = lin - 192;
    m0 = (l2 >> 3) * 256;
    n0 = (l2 & 7) * 256;
    Ag = Gmb; Bg = Wgb; biasv = bg;
    Kd = 256; KT = 4; nit2 = 2;
  }
  const int tid = threadIdx.x, lane = tid & 63, w = tid >> 6;
  const int w8 = w * 8, ln3 = lane >> 3, ch = lane & 7;
  const int fr = lane & 15, ck = lane >> 4;
  const int wm64 = (w >> 2) * 64;   // row sub-offset within each 128-half
  const int wn32 = (w & 3) * 32;    // col sub-offset within each 128-half

  f32x4 acc[8][4];
  const f32x4 fzero = {0.f, 0.f, 0.f, 0.f};
#pragma unroll
  for (int i = 0; i < 8; ++i)
#pragma unroll
    for (int j = 0; j < 4; ++j) acc[i][j] = fzero;

  // stage one 128x64 half (16 KB): 2 x global_load_lds_dwordx4 per thread.
  auto stageA = [&](int buf, int mh, int kt) {
    const int k0 = kt * 64;
#pragma unroll
    for (int l = 0; l < 2; ++l) {
      const int rit = mh * 128 + l * 64 + w8 + ln3;  // rit&7 == ln3
      async_copy16(Ag + (size_t)(m0 + rit) * Kd + k0 + ((ch ^ ln3) << 3),
                   (char*)&AS[buf][0][0] + ((mh * 128 + l * 64 + w8) << 7));
    }
  };
  auto stageB = [&](int buf, int nh, int kt) {
    const int k0 = kt * 64;
#pragma unroll
    for (int l = 0; l < 2; ++l) {
      const int rit = nh * 128 + l * 64 + w8 + ln3;
      async_copy16(Bg + (size_t)(n0 + rit) * Kd + k0 + ((ch ^ ln3) << 3),
                   (char*)&BS[buf][0][0] + ((nh * 128 + l * 64 + w8) << 7));
    }
  };

  bf16x8 af[4][2], bA[2][2], bB[2][2];
  auto ldA = [&](int buf, int mh) {
#pragma unroll
    for (int i = 0; i < 4; ++i)
#pragma unroll
      for (int ks = 0; ks < 2; ++ks)
        af[i][ks] = *(const bf16x8*)(
            &AS[buf][mh * 128 + wm64 + i * 16 + fr][0] +
            (((ks * 4 + ck) ^ (fr & 7)) << 3));
  };
  auto ldB = [&](bf16x8 (&dst)[2][2], int buf, int nh) {
#pragma unroll
    for (int j = 0; j < 2; ++j)
#pragma unroll
      for (int ks = 0; ks < 2; ++ks)
        dst[j][ks] = *(const bf16x8*)(
            &BS[buf][nh * 128 + wn32 + j * 16 + fr][0] +
            (((ks * 4 + ck) ^ (fr & 7)) << 3));
  };

#define BAR() __builtin_amdgcn_s_barrier()
#define LGKM0() asm volatile("s_waitcnt lgkmcnt(0)" ::: "memory")
#define MMAQ(MH, NH, BF)                                                      \
  __builtin_amdgcn_s_setprio(1);                                              \
  _Pragma("unroll") for (int i_ = 0; i_ < 4; ++i_) {                          \
    _Pragma("unroll") for (int j_ = 0; j_ < 2; ++j_) {                        \
      acc[(MH) * 4 + i_][(NH) * 2 + j_] = mfma16x16x32(                       \
          af[i_][0], BF[j_][0], acc[(MH) * 4 + i_][(NH) * 2 + j_]);           \
      acc[(MH) * 4 + i_][(NH) * 2 + j_] = mfma16x16x32(                       \
          af[i_][1], BF[j_][1], acc[(MH) * 4 + i_][(NH) * 2 + j_]);           \
    }                                                                         \
  }                                                                           \
  __builtin_amdgcn_s_setprio(0);

  // Prologue: K-tile 0 fully + first half of K-tile 1; wait the oldest 8
  // loads (tile 0), leave tile-1 halves in flight.
  stageA(0, 0, 0); stageB(0, 0, 0); stageB(0, 1, 0); stageA(0, 1, 0);
  stageA(1, 0, 1); stageB(1, 0, 1);
  asm volatile("s_waitcnt vmcnt(4)" ::: "memory");
  BAR();

  for (int it = 0; it < nit2; ++it) {
    const int kodd = 2 * it + 1;                          // buf1, this iter
    const int kn0 = (2 * it + 2 < KT) ? 2 * it + 2 : KT - 1;  // buf0 next
    const int kn1 = (2 * it + 3 < KT) ? 2 * it + 3 : KT - 1;  // buf1 next
    // Tail iterations clamp (re-stage last tile) instead of skipping so the
    // vmcnt(4) counting below stays invariant; results never read.

    // -- phase 1: quad (mh0,nh0) of buf0
    ldA(0, 0); ldB(bA, 0, 0);
    stageB(1, 1, kodd);
    asm volatile("s_waitcnt lgkmcnt(8)");
    BAR(); LGKM0();
    MMAQ(0, 0, bA);
    BAR();
    // -- phase 2: (mh0,nh1) buf0
    ldB(bB, 0, 1);
    stageA(1, 1, kodd);
    BAR(); LGKM0();
    MMAQ(0, 1, bB);
    BAR();
    // -- phase 3: (mh1,nh0) buf0
    ldA(0, 1);
    stageA(0, 0, kn0);
    BAR(); LGKM0();
    MMAQ(1, 0, bA);
    BAR();
    // -- phase 4: (mh1,nh1) buf0; counted wait covers phases 5-8 reads
    stageB(0, 0, kn0);
    asm volatile("s_waitcnt vmcnt(4)" ::: "memory");
    BAR();
    MMAQ(1, 1, bB);
    BAR();
    // -- phase 5: (mh0,nh0) buf1
    ldA(1, 0); ldB(bA, 1, 0);
    stageB(0, 1, kn0);
    asm volatile("s_waitcnt lgkmcnt(8)");
    BAR(); LGKM0();
    MMAQ(0, 0, bA);
    BAR();
    // -- phase 6: (mh0,nh1) buf1
    ldB(bB, 1, 1);
    stageA(0, 1, kn0);
    BAR(); LGKM0();
    MMAQ(0, 1, bB);
    BAR();
    // -- phase 7: (mh1,nh0) buf1
    ldA(1, 1);
    stageA(1, 0, kn1);
    BAR(); LGKM0();
    MMAQ(1, 0, bA);
    BAR();
    // -- phase 8: (mh1,nh1) buf1; counted wait covers next iter phases 1-4
    stageB(1, 0, kn1);
    asm volatile("s_waitcnt vmcnt(4)" ::: "memory");
    BAR();
    MMAQ(1, 1, bB);
    BAR();
  }
  // Drain remaining staged loads before retire (LDS-write vs next block).
  asm volatile("s_waitcnt vmcnt(0)" ::: "memory");

  const int erow = (lane >> 4) * 4, ecol = lane & 15;
  // fragment (ai,bj): row = m0 + (ai>>2)*128 + wm64 + (ai&3)*16,
  //                   col = n0 + (bj>>1)*128 + wn32 + (bj&1)*16
  if (!isqkv) {
#pragma unroll
    for (int ai = 0; ai < 8; ++ai) {
      const int gm0 = m0 + (ai >> 2) * 128 + wm64 + (ai & 3) * 16 + erow;
#pragma unroll
      for (int bj = 0; bj < 4; ++bj) {
        const int gn = n0 + (bj >> 1) * 128 + wn32 + (bj & 1) * 16 + ecol;
        const float bv = biasv[gn];
#pragma unroll
        for (int r = 0; r < 4; ++r)
          biasS[(size_t)(gm0 + r) * 2048 + gn] =
              __float2bfloat16((acc[ai][bj][r] + bv) * LOG2E);
      }
    }
  } else if (n0 < 2048) {
    const float sc = (n0 < 1024) ? 0.125f * LOG2E : 1.0f;
#pragma unroll
    for (int ai = 0; ai < 8; ++ai) {
      const int gm0 = m0 + (ai >> 2) * 128 + wm64 + (ai & 3) * 16 + erow;
#pragma unroll
      for (int bj = 0; bj < 4; ++bj) {
        const int gn = n0 + (bj >> 1) * 128 + wn32 + (bj & 1) * 16 + ecol;
        const float bv = biasv[gn];
#pragma unroll
        for (int r = 0; r < 4; ++r)
          QKb[(size_t)(gm0 + r) * 2048 + gn] =
              __float2bfloat16((acc[ai][bj][r] + bv) * sc);
      }
    }
  } else {
#pragma unroll
    for (int ai = 0; ai < 8; ++ai) {
      const int gm0 = m0 + (ai >> 2) * 128 + wm64 + (ai & 3) * 16 + erow;
      const int bb = gm0 >> 11;
      const int t = gm0 & 2047;
#pragma unroll
      for (int bj = 0; bj < 4; ++bj) {
        const int gn = n0 + (bj >> 1) * 128 + wn32 + (bj & 1) * 16 + ecol;
        const float bv = biasv[gn];
        const int d = gn - 2048;
        __align__(8) bf16 tmp[4];
#pragma unroll
        for (int r = 0; r < 4; ++r)
          tmp[r] = __float2bfloat16(acc[ai][bj][r] + bv);
        *(ushort4*)(Vt + ((size_t)(bb * 1024 + d)) * 2048 + t) =
            *(const ushort4*)tmp;
      }
    }
  }
#undef MMAQ
#undef LGKM0
#undef BAR
}

// ---------------------------------------------------------------------------
// Out projection: C(4096x1024) f32 = A(4096x1024)@(1024x1024)^T + bo.
// 128x64 tile, BK=64, dbuf, XCD-swizzled (2 n-blocks per XCD). 1D grid 512.
__global__ __launch_bounds__(256) void gemm_out(const bf16* __restrict__ A,
                                                const bf16* __restrict__ W,
                                                const float* __restrict__ biasv,
                                                float* __restrict__ C) {
  __shared__ __align__(16) bf16 As[2][128 * 64];  // 2 x 16 KB
  __shared__ __align__(16) bf16 Bs[2][64 * 64];   // 2 x 8 KB
  const int lin = blockIdx.x;
  const int xcd = lin & 7;
  const int kk = lin >> 3;  // 0..63
  const int m0 = (kk >> 1) * 128;
  const int n0 = (xcd * 2 + (kk & 1)) * 64;
  const int tid = threadIdx.x, lane = tid & 63, w = tid >> 6;
  const int wm = (w >> 1) * 64, wn = (w & 1) * 32;
  const int fr = lane & 15;
  const int ck = lane >> 4;

  f32x4 acc[4][2];
  const f32x4 fzero = {0.f, 0.f, 0.f, 0.f};
#pragma unroll
  for (int i = 0; i < 4; ++i)
#pragma unroll
    for (int j = 0; j < 2; ++j) acc[i][j] = fzero;

  auto stage = [&](int it, int buf) {
    const int k0 = it * 64;
#pragma unroll
    for (int is = 0; is < 4; ++is) {
      const int off = is * 4096 + w * 1024;
      const int row = (off >> 7) + (lane >> 3);
      const int sch = ((lane & 7) ^ (row & 7)) * 8;
      async_copy16(A + (size_t)(m0 + row) * 1024 + k0 + sch,
                   (char*)As[buf] + off);
      if (is < 2)
        async_copy16(W + (size_t)(n0 + row) * 1024 + k0 + sch,
                     (char*)Bs[buf] + off);
    }
  };

  stage(0, 0);
  __syncthreads();
  for (int it = 0; it < 16; ++it) {
    const int cur = it & 1;
    if (it + 1 < 16) stage(it + 1, cur ^ 1);
#pragma unroll
    for (int ks = 0; ks < 2; ++ks) {
      bf16x8 af[4], bfr[2];
      const int swk0 = (((ks * 4 + ck) ^ (fr & 7))) * 8;
#pragma unroll
      for (int i = 0; i < 4; ++i)
        af[i] = *(const bf16x8*)(As[cur] + (wm + i * 16 + fr) * 64 + swk0);
#pragma unroll
      for (int j = 0; j < 2; ++j)
        bfr[j] = *(const bf16x8*)(Bs[cur] + (wn + j * 16 + fr) * 64 + swk0);
#pragma unroll
      for (int i = 0; i < 4; ++i)
#pragma unroll
        for (int j = 0; j < 2; ++j)
          acc[i][j] = mfma16x16x32(af[i], bfr[j], acc[i][j]);
    }
    __syncthreads();
  }
  const int erow = (lane >> 4) * 4;
  const int ecol = lane & 15;
#pragma unroll
  for (int i = 0; i < 4; ++i) {
    const int gm0 = m0 + wm + i * 16 + erow;
#pragma unroll
    for (int j = 0; j < 2; ++j) {
      const int gn = n0 + wn + j * 16 + ecol;
      const float bv = biasv[gn];
#pragma unroll
      for (int r = 0; r < 4; ++r)
        C[(size_t)(gm0 + r) * 1024 + gn] = acc[i][j][r] + bv;
    }
  }
}

// ---------------------------------------------------------------------------
// Flash attention, S^T formulation, no-max softmax, key-split, TWO HEADS per
// block: one bias fetch serves both heads' S C-init (bias has no head index)
// -> bias traffic and bias load latency halve. LDS-P (proven R7 path).
// Per key-iter: stage K/V for both heads (single-buffer, 2-barrier), then
// per head: S = K.Q^T + bias, exp -> Ps (stride 72, conflict-free), PV.
// Ps reused serially across heads within the wave (no barrier needed).
// 1D grid 512 = 16 qblk x 2 half x 8 head-pairs x 2 b. LDS 50.7 KB.
__global__ __launch_bounds__(256) void flash_attn(
    const bf16* __restrict__ Qm, const bf16* __restrict__ Km,
    const bf16* __restrict__ Vtm, const bf16* __restrict__ biasS,
    float* __restrict__ Op0, float* __restrict__ Op1,
    float* __restrict__ lpart) {
  __shared__ __align__(16) bf16 Ks[2][64 * 64];   // per head, 16 KB
  __shared__ __align__(16) bf16 Vs[2][64 * 64];   // per head, 16 KB
  __shared__ __align__(16) bf16 Ps[4 * 32 * 72];  // per-wave P^T, 18 KB
  const int lin = blockIdx.x;
  const int xcd = lin & 7;
  const int kk = lin >> 3;        // 0..63
  const int cl = kk & 1;
  const int r2 = kk >> 1;         // 0..31
  const int half = r2 & 1;
  const int q0 = (r2 >> 1) * 128;
  const int combo = xcd * 2 + cl; // 0..15
  const int hp = combo & 7;       // head pair
  const int b = combo >> 3;
  const int tid = threadIdx.x, lane = tid & 63, w = tid >> 6;
  const int ql = lane & 15, qk = lane >> 4;
  const int T = 2048, D = 1024;
  const int sw0 = (qk ^ (ql & 7)) * 8;
  const int sw1 = ((qk + 4) ^ (ql & 7)) * 8;

  // Q B-frags for both heads: B[n=q][k=d], 2 q-subtiles x 2 k-steps
  bf16x8 qf[2][2][2];  // [head][qt][ks]
#pragma unroll
  for (int hh = 0; hh < 2; ++hh)
#pragma unroll
    for (int qt = 0; qt < 2; ++qt)
#pragma unroll
      for (int ks = 0; ks < 2; ++ks)
        qf[hh][qt][ks] = *(const bf16x8*)(
            Qm + (size_t)(b * T + q0 + w * 32 + qt * 16 + ql) * 2048 +
            (hp * 2 + hh) * 64 + ks * 32 + qk * 8);

  f32x4 acc[2][4][2];  // [head][dt][qt]
  const f32x4 fzero = {0.f, 0.f, 0.f, 0.f};
#pragma unroll
  for (int hh = 0; hh < 2; ++hh)
#pragma unroll
    for (int dt = 0; dt < 4; ++dt)
#pragma unroll
      for (int qt = 0; qt < 2; ++qt) acc[hh][dt][qt] = fzero;
  float lp[2][2] = {{0.f, 0.f}, {0.f, 0.f}};

  const bf16* kbase0 = Km + (size_t)(b * T) * 2048 + (hp * 2) * 64;
  const bf16* vbase0 = Vtm + (size_t)(b * D + hp * 2 * 64) * 2048;
  const bf16* bb0 = biasS + (size_t)(b * T + q0 + w * 32 + ql) * 2048 + qk * 4;
  bf16* pb = Ps + w * 2304;

  for (int j = 0; j < 16; ++j) {
    const int jj = half * 16 + j;  // global key-block
    __syncthreads();
#pragma unroll
    for (int hh = 0; hh < 2; ++hh)
#pragma unroll
      for (int is = 0; is < 2; ++is) {
        const int off = is * 4096 + w * 1024;
        const int row = (off >> 7) + (lane >> 3);
        const int sch = ((lane & 7) ^ (row & 7)) * 8;
        async_copy16(kbase0 + (size_t)(jj * 64 + row) * 2048 + hh * 64 + sch,
                     (char*)Ks[hh] + off);
        async_copy16(vbase0 + (size_t)(hh * 64 + row) * 2048 + jj * 64 + sch,
                     (char*)Vs[hh] + off);
      }
    // bias prefetch: ONE fetch for BOTH heads (overlaps staging drain)
    ushort4 bq[2][4];
#pragma unroll
    for (int qt = 0; qt < 2; ++qt)
#pragma unroll
      for (int jt = 0; jt < 4; ++jt)
        bq[qt][jt] = *(const ushort4*)(bb0 + (size_t)qt * 16 * 2048 + jj * 64 +
                                       jt * 16);
    __syncthreads();
#pragma unroll
    for (int hh = 0; hh < 2; ++hh) {
      const bf16* ksp = Ks[hh];
      const bf16* vsp = Vs[hh];
      // S^T tiles: rows=key, cols=q; bias as MFMA C-init (shared)
#pragma unroll
      for (int jt = 0; jt < 4; ++jt) {
        const bf16x8 kf0 = *(const bf16x8*)(ksp + (jt * 16 + ql) * 64 + sw0);
        const bf16x8 kf1 = *(const bf16x8*)(ksp + (jt * 16 + ql) * 64 + sw1);
#pragma unroll
        for (int qt = 0; qt < 2; ++qt) {
          f32x4 c;
          c[0] = bfu2f(bq[qt][jt].x); c[1] = bfu2f(bq[qt][jt].y);
          c[2] = bfu2f(bq[qt][jt].z); c[3] = bfu2f(bq[qt][jt].w);
          c = mfma16x16x32(kf0, qf[hh][qt][0], c);
          c = mfma16x16x32(kf1, qf[hh][qt][1], c);
          __align__(8) bf16 t4[4];
#pragma unroll
          for (int r = 0; r < 4; ++r) {
            const float pv = __builtin_amdgcn_exp2f(c[r]);
            lp[hh][qt] += pv;
            t4[r] = __float2bfloat16(pv);
          }
          *(ushort4*)(pb + (qt * 16 + ql) * 72 + jt * 16 + qk * 4) =
              *(const ushort4*)t4;
        }
      }
      // O[q][d] += P.V^T ; V-frags shared across q-subtiles
#pragma unroll
      for (int ks = 0; ks < 2; ++ks) {
        const bf16x8 pf0 = *(const bf16x8*)(pb + ql * 72 + ks * 32 + qk * 8);
        const bf16x8 pf1 =
            *(const bf16x8*)(pb + (16 + ql) * 72 + ks * 32 + qk * 8);
        const int sw = ks ? sw1 : sw0;
#pragma unroll
        for (int dt = 0; dt < 4; ++dt) {
          const bf16x8 vf = *(const bf16x8*)(vsp + (dt * 16 + ql) * 64 + sw);
          acc[hh][dt][0] = mfma16x16x32(pf0, vf, acc[hh][dt][0]);
          acc[hh][dt][1] = mfma16x16x32(pf1, vf, acc[hh][dt][1]);
        }
      }
    }
  }
  // l partials: reduce across quads (lane's p-values all share q = ...+ql)
#pragma unroll
  for (int hh = 0; hh < 2; ++hh)
#pragma unroll
    for (int qt = 0; qt < 2; ++qt) {
      lp[hh][qt] += __shfl_xor(lp[hh][qt], 16);
      lp[hh][qt] += __shfl_xor(lp[hh][qt], 32);
    }
  if (qk == 0) {
#pragma unroll
    for (int hh = 0; hh < 2; ++hh)
#pragma unroll
      for (int qt = 0; qt < 2; ++qt)
        lpart[half * 65536 + (b * 16 + hp * 2 + hh) * 2048 + q0 + w * 32 +
              qt * 16 + ql] = lp[hh][qt];
  }
  float* Op = half ? Op1 : Op0;
#pragma unroll
  for (int hh = 0; hh < 2; ++hh)
#pragma unroll
    for (int qt = 0; qt < 2; ++qt)
#pragma unroll
      for (int r = 0; r < 4; ++r) {
        const size_t orow =
            (size_t)(b * T + q0 + w * 32 + qt * 16 + qk * 4 + r);
#pragma unroll
        for (int dt = 0; dt < 4; ++dt)
          Op[orow * 1024 + (hp * 2 + hh) * 64 + dt * 16 + ql] =
              acc[hh][dt][qt][r];
      }
}

// ---------------------------------------------------------------------------
// Combine key-half partials: AOut = bf16((O0+O1) / (l0+l1)). grid 4096 x 256.
__global__ __launch_bounds__(256) void combine(const float* __restrict__ O0,
                                               const float* __restrict__ O1,
                                               const float* __restrict__ lpart,
                                               bf16* __restrict__ AOut) {
  const int idx = blockIdx.x * 256 + threadIdx.x;  // 0..1048575
  const int row = idx >> 8;
  const int col = (idx & 255) * 4;
  const int b = row >> 11, q = row & 2047, h = col >> 6;
  const int li = (b * 16 + h) * 2048 + q;
  const float inv = __builtin_amdgcn_rcpf(lpart[li] + lpart[65536 + li]);
  const float4 a = *(const float4*)(O0 + (size_t)row * 1024 + col);
  const float4 c = *(const float4*)(O1 + (size_t)row * 1024 + col);
  __align__(8) bf16 t[4] = {
      __float2bfloat16((a.x + c.x) * inv), __float2bfloat16((a.y + c.y) * inv),
      __float2bfloat16((a.z + c.z) * inv), __float2bfloat16((a.w + c.w) * inv)};
  *(ushort4*)(AOut + (size_t)row * 1024 + col) = *(const ushort4*)t;
}

// ---------------------------------------------------------------------------
extern "C" void kernel_launch(void* const* d_in, const int* in_sizes, int n_in,
                              void* d_out, int out_size, void* d_ws,
                              size_t ws_size, hipStream_t stream) {
  (void)in_sizes; (void)n_in; (void)out_size; (void)ws_size;
  const float* Hx = (const float*)d_in[0];
  const float* Hf = (const float*)d_in[1];
  const float* Gm = (const float*)d_in[2];
  const float* Wg = (const float*)d_in[3];
  const float* bg = (const float*)d_in[4];
  const float* Wq = (const float*)d_in[5];
  const float* bq = (const float*)d_in[6];
  const float* Wk = (const float*)d_in[7];
  const float* bk = (const float*)d_in[8];
  const float* Wv = (const float*)d_in[9];
  const float* bv = (const float*)d_in[10];
  const float* Wo = (const float*)d_in[11];
  const float* bo = (const float*)d_in[12];
  float* out = (float*)d_out;

  char* p = (char*)d_ws;
  bf16* hcat = (bf16*)p;   p += (size_t)4096 * 2048 * 2;  // (B*T, 2D)
  bf16* QKb = (bf16*)p;    p += (size_t)4096 * 2048 * 2;  // (B*T, Q|K)
  bf16* Vtb = (bf16*)p;    p += (size_t)4096 * 1024 * 2;  // (B, D, T)
  bf16* biasS = (bf16*)p;  p += (size_t)4096 * 2048 * 2;  // (B*T, T) * log2e
  bf16* AOut = (bf16*)p;   p += (size_t)4096 * 1024 * 2;
  bf16* Wqkvb = (bf16*)p;  p += (size_t)3072 * 2048 * 2;  // (3N, K) packed
  bf16* Wob = (bf16*)p;    p += (size_t)1024 * 1024 * 2;
  bf16* Wgb = (bf16*)p;    p += (size_t)2048 * 256 * 2;
  bf16* Gmb = (bf16*)p;    p += (size_t)4096 * 256 * 2;
  float* qkvbias = (float*)p; p += (size_t)3072 * 4;
  float* Op1 = (float*)p;  p += (size_t)4096 * 1024 * 4;  // key-half-1 partial
  float* lpart = (float*)p; p += (size_t)2 * 65536 * 4;   // l partials
  float* Op0 = (float*)hcat;  // hcat is dead after gemm_qkv_bias; 16.8 MB fits

  pack_hx<<<dim3(32, 16, 2), 256, 0, stream>>>(Hx, hcat);
  pack_all<<<dim3(12803), 256, 0, stream>>>(Hf, Wq, Wk, Wv, Wo, Wg, Gm, bq, bk,
                                            bv, hcat, Wqkvb, Wob, Wgb, Gmb,
                                            qkvbias);
  // QKV projection + attention-bias GEMM, 256^2 8-phase, one dispatch
  gemm_qkv_bias<<<dim3(320), 512, 0, stream>>>(hcat, Wqkvb, qkvbias, Gmb,
                                               Wgb, bg, QKb, Vtb, biasS);
  // fused attention, key-split halves, 2 heads/block (bias shared)
  flash_attn<<<dim3(512), 256, 0, stream>>>(QKb, QKb + 1024, Vtb, biasS,
                                            Op0, Op1, lpart);
  // combine partials -> AOut bf16
  combine<<<dim3(4096), 256, 0, stream>>>(Op0, Op1, lpart, AOut);
  // output projection (fp32 out), XCD-swizzled
  gemm_out<<<dim3(512), 256, 0, stream>>>(AOut, Wob, bo, out);
}

// Round 10
// 275.531 us; speedup vs baseline: 1.1298x; 1.0096x over previous
//
#include <hip/hip_runtime.h>
#include <hip/hip_bf16.h>

using bf16 = __hip_bfloat16;
typedef __attribute__((ext_vector_type(8))) __bf16 bf16x8;
typedef __attribute__((ext_vector_type(4))) float f32x4;

#define GLB_AS(p) ((const __attribute__((address_space(1))) unsigned int*)(p))
#define LDS_AS(p) ((__attribute__((address_space(3))) unsigned int*)(p))

__device__ __forceinline__ void async_copy16(const void* g, void* l) {
  __builtin_amdgcn_global_load_lds(GLB_AS(g), LDS_AS(l), 16, 0, 0);
}

__device__ __forceinline__ f32x4 mfma16x16x32(bf16x8 a, bf16x8 b, f32x4 c) {
  return __builtin_amdgcn_mfma_f32_16x16x32_bf16(a, b, c, 0, 0, 0);
}

__device__ __forceinline__ float bfu2f(unsigned short u) {
  union { unsigned int i; float f; } x;
  x.i = (unsigned int)u << 16;
  return x.f;
}

#define LOG2E 1.44269504f

// ---------------------------------------------------------------------------
// Hx (B,D,T) f32 -> hcat[b][t][0..1023] bf16 (row stride 2048). LDS transpose.
__global__ __launch_bounds__(256) void pack_hx(const float* __restrict__ Hx,
                                               bf16* __restrict__ hcat) {
  __shared__ float tile[64][65];
  const int t0 = blockIdx.x * 64, d0 = blockIdx.y * 64, b = blockIdx.z;
  const int c = threadIdx.x & 63, r0 = threadIdx.x >> 6;
#pragma unroll
  for (int i = 0; i < 16; ++i) {
    const int rd = r0 + i * 4;
    tile[rd][c] = Hx[((size_t)(b * 1024 + d0 + rd)) * 2048 + t0 + c];
  }
  __syncthreads();
#pragma unroll
  for (int i = 0; i < 16; ++i) {
    const int ct = r0 + i * 4;
    hcat[((size_t)(b * 2048 + t0 + ct)) * 2048 + d0 + c] =
        __float2bfloat16(tile[c][ct]);
  }
}

// ---------------------------------------------------------------------------
// One kernel for all f32->bf16 packs + the QKV bias concat (f32 copy).
__global__ __launch_bounds__(256) void pack_all(
    const float* __restrict__ Hf, const float* __restrict__ Wq,
    const float* __restrict__ Wk, const float* __restrict__ Wv,
    const float* __restrict__ Wo, const float* __restrict__ Wg,
    const float* __restrict__ Gm, const float* __restrict__ bq,
    const float* __restrict__ bk, const float* __restrict__ bv,
    bf16* __restrict__ hcat, bf16* __restrict__ Wqkvb, bf16* __restrict__ Wob,
    bf16* __restrict__ Wgb, bf16* __restrict__ Gmb,
    float* __restrict__ qkvbias) {
  const int gid = blockIdx.x * 256 + threadIdx.x;
  const float* src = nullptr;
  bf16* dst = nullptr;
  int lg = 0, ldo = 0, off = 0, idx = 0;
  bool zero = false;
  if (gid < 1048576) { idx = gid; src = Hf; dst = hcat; lg = 8; ldo = 2048; off = 1024; }
  else if (gid < 1572864) { idx = gid - 1048576; src = Wq; dst = Wqkvb; lg = 9; ldo = 2048; }
  else if (gid < 2097152) { idx = gid - 1572864; src = Wk; dst = Wqkvb + (size_t)1024 * 2048; lg = 9; ldo = 2048; }
  else if (gid < 2359296) { idx = gid - 2097152; src = Wv; dst = Wqkvb + (size_t)2048 * 2048; lg = 8; ldo = 2048; }
  else if (gid < 2621440) { idx = gid - 2359296; zero = true; dst = Wqkvb + (size_t)2048 * 2048 + 1024; lg = 8; ldo = 2048; }
  else if (gid < 2883584) { idx = gid - 2621440; src = Wo; dst = Wob; lg = 8; ldo = 1024; }
  else if (gid < 3014656) { idx = gid - 2883584; src = Wg; dst = Wgb; lg = 6; ldo = 256; }
  else if (gid < 3276800) { idx = gid - 3014656; src = Gm; dst = Gmb; lg = 6; ldo = 256; }
  else if (gid < 3277056) { const int i = gid - 3276800; ((float4*)qkvbias)[i] = ((const float4*)bq)[i]; return; }
  else if (gid < 3277312) { const int i = gid - 3277056; ((float4*)(qkvbias + 1024))[i] = ((const float4*)bk)[i]; return; }
  else { const int i = gid - 3277312; ((float4*)(qkvbias + 2048))[i] = ((const float4*)bv)[i]; return; }
  const int row = idx >> lg, c = idx & ((1 << lg) - 1);
  bf16* o = dst + (size_t)row * ldo + off + c * 4;
  __align__(8) bf16 tmp[4];
  if (zero) {
    tmp[0] = tmp[1] = tmp[2] = tmp[3] = __float2bfloat16(0.f);
  } else {
    const float4 v = ((const float4*)src)[(size_t)idx];
    tmp[0] = __float2bfloat16(v.x); tmp[1] = __float2bfloat16(v.y);
    tmp[2] = __float2bfloat16(v.z); tmp[3] = __float2bfloat16(v.w);
  }
  *(ushort4*)o = *(const ushort4*)tmp;
}

// ---------------------------------------------------------------------------
// Combined QKV + bias GEMM, 256x256 tile, BK=64, 8-phase counted-vmcnt
// schedule (T3+T4) + setprio (T5), chunk-XOR swizzle (T2) kept on both sides.
// 512 threads = 8 waves (2M x 4N, half-aligned quadrants so each phase's
// MFMA reads exactly one staged A-half and one B-half).
// Grid 320 = 192 QKV tiles (XCD-grouped 4m x 6n) + 128 bias tiles.
// LDS 128 KiB -> 1 block/CU.
__global__ __launch_bounds__(512, 2) void gemm_qkv_bias(
    const bf16* __restrict__ hcat, const bf16* __restrict__ Wqkv,
    const float* __restrict__ qkvbias, const bf16* __restrict__ Gmb,
    const bf16* __restrict__ Wgb, const float* __restrict__ bg,
    bf16* __restrict__ QKb, bf16* __restrict__ Vt, bf16* __restrict__ biasS) {
  __shared__ __align__(16) bf16 AS[2][256][64];  // 64 KB (even/odd K-tile)
  __shared__ __align__(16) bf16 BS[2][256][64];  // 64 KB
  const int lin = blockIdx.x;
  const bool isqkv = lin < 192;
  int m0, n0, Kd, KT, nit2;
  const bf16 *Ag, *Bg;
  const float* biasv;
  if (isqkv) {
    const int xcd = lin & 7, kk = lin >> 3;  // 24 tiles per XCD: 4m x 6n
    const int mloc = kk / 6, nloc = kk - mloc * 6;
    m0 = ((xcd >> 1) * 4 + mloc) * 256;
    n0 = ((xcd & 1) * 6 + nloc) * 256;
    Ag = hcat; Bg = Wqkv; biasv = qkvbias;
    Kd = 2048; KT = 32; nit2 = 16;
  } else {
    const int l2 = lin - 192;
    m0 = (l2 >> 3) * 256;
    n0 = (l2 & 7) * 256;
    Ag = Gmb; Bg = Wgb; biasv = bg;
    Kd = 256; KT = 4; nit2 = 2;
  }
  const int tid = threadIdx.x, lane = tid & 63, w = tid >> 6;
  const int w8 = w * 8, ln3 = lane >> 3, ch = lane & 7;
  const int fr = lane & 15, ck = lane >> 4;
  const int wm64 = (w >> 2) * 64;   // row sub-offset within each 128-half
  const int wn32 = (w & 3) * 32;    // col sub-offset within each 128-half

  f32x4 acc[8][4];
  const f32x4 fzero = {0.f, 0.f, 0.f, 0.f};
#pragma unroll
  for (int i = 0; i < 8; ++i)
#pragma unroll
    for (int j = 0; j < 4; ++j) acc[i][j] = fzero;

  // stage one 128x64 half (16 KB): 2 x global_load_lds_dwordx4 per thread.
  auto stageA = [&](int buf, int mh, int kt) {
    const int k0 = kt * 64;
#pragma unroll
    for (int l = 0; l < 2; ++l) {
      const int rit = mh * 128 + l * 64 + w8 + ln3;  // rit&7 == ln3
      async_copy16(Ag + (size_t)(m0 + rit) * Kd + k0 + ((ch ^ ln3) << 3),
                   (char*)&AS[buf][0][0] + ((mh * 128 + l * 64 + w8) << 7));
    }
  };
  auto stageB = [&](int buf, int nh, int kt) {
    const int k0 = kt * 64;
#pragma unroll
    for (int l = 0; l < 2; ++l) {
      const int rit = nh * 128 + l * 64 + w8 + ln3;
      async_copy16(Bg + (size_t)(n0 + rit) * Kd + k0 + ((ch ^ ln3) << 3),
                   (char*)&BS[buf][0][0] + ((nh * 128 + l * 64 + w8) << 7));
    }
  };

  bf16x8 af[4][2], bA[2][2], bB[2][2];
  auto ldA = [&](int buf, int mh) {
#pragma unroll
    for (int i = 0; i < 4; ++i)
#pragma unroll
      for (int ks = 0; ks < 2; ++ks)
        af[i][ks] = *(const bf16x8*)(
            &AS[buf][mh * 128 + wm64 + i * 16 + fr][0] +
            (((ks * 4 + ck) ^ (fr & 7)) << 3));
  };
  auto ldB = [&](bf16x8 (&dst)[2][2], int buf, int nh) {
#pragma unroll
    for (int j = 0; j < 2; ++j)
#pragma unroll
      for (int ks = 0; ks < 2; ++ks)
        dst[j][ks] = *(const bf16x8*)(
            &BS[buf][nh * 128 + wn32 + j * 16 + fr][0] +
            (((ks * 4 + ck) ^ (fr & 7)) << 3));
  };

#define BAR() __builtin_amdgcn_s_barrier()
#define LGKM0() asm volatile("s_waitcnt lgkmcnt(0)" ::: "memory")
#define MMAQ(MH, NH, BF)                                                      \
  __builtin_amdgcn_s_setprio(1);                                              \
  _Pragma("unroll") for (int i_ = 0; i_ < 4; ++i_) {                          \
    _Pragma("unroll") for (int j_ = 0; j_ < 2; ++j_) {                        \
      acc[(MH) * 4 + i_][(NH) * 2 + j_] = mfma16x16x32(                       \
          af[i_][0], BF[j_][0], acc[(MH) * 4 + i_][(NH) * 2 + j_]);           \
      acc[(MH) * 4 + i_][(NH) * 2 + j_] = mfma16x16x32(                       \
          af[i_][1], BF[j_][1], acc[(MH) * 4 + i_][(NH) * 2 + j_]);           \
    }                                                                         \
  }                                                                           \
  __builtin_amdgcn_s_setprio(0);

  // Prologue: K-tile 0 fully + first half of K-tile 1; wait the oldest 8
  // loads (tile 0), leave tile-1 halves in flight.
  stageA(0, 0, 0); stageB(0, 0, 0); stageB(0, 1, 0); stageA(0, 1, 0);
  stageA(1, 0, 1); stageB(1, 0, 1);
  asm volatile("s_waitcnt vmcnt(4)" ::: "memory");
  BAR();

  for (int it = 0; it < nit2; ++it) {
    const int kodd = 2 * it + 1;                          // buf1, this iter
    const int kn0 = (2 * it + 2 < KT) ? 2 * it + 2 : KT - 1;  // buf0 next
    const int kn1 = (2 * it + 3 < KT) ? 2 * it + 3 : KT - 1;  // buf1 next
    // Tail iterations clamp (re-stage last tile) instead of skipping so the
    // vmcnt(4) counting below stays invariant; results never read.

    // -- phase 1: quad (mh0,nh0) of buf0
    ldA(0, 0); ldB(bA, 0, 0);
    stageB(1, 1, kodd);
    asm volatile("s_waitcnt lgkmcnt(8)");
    BAR(); LGKM0();
    MMAQ(0, 0, bA);
    BAR();
    // -- phase 2: (mh0,nh1) buf0
    ldB(bB, 0, 1);
    stageA(1, 1, kodd);
    BAR(); LGKM0();
    MMAQ(0, 1, bB);
    BAR();
    // -- phase 3: (mh1,nh0) buf0
    ldA(0, 1);
    stageA(0, 0, kn0);
    BAR(); LGKM0();
    MMAQ(1, 0, bA);
    BAR();
    // -- phase 4: (mh1,nh1) buf0; counted wait covers phases 5-8 reads
    stageB(0, 0, kn0);
    asm volatile("s_waitcnt vmcnt(4)" ::: "memory");
    BAR();
    MMAQ(1, 1, bB);
    BAR();
    // -- phase 5: (mh0,nh0) buf1
    ldA(1, 0); ldB(bA, 1, 0);
    stageB(0, 1, kn0);
    asm volatile("s_waitcnt lgkmcnt(8)");
    BAR(); LGKM0();
    MMAQ(0, 0, bA);
    BAR();
    // -- phase 6: (mh0,nh1) buf1
    ldB(bB, 1, 1);
    stageA(0, 1, kn0);
    BAR(); LGKM0();
    MMAQ(0, 1, bB);
    BAR();
    // -- phase 7: (mh1,nh0) buf1
    ldA(1, 1);
    stageA(1, 0, kn1);
    BAR(); LGKM0();
    MMAQ(1, 0, bA);
    BAR();
    // -- phase 8: (mh1,nh1) buf1; counted wait covers next iter phases 1-4
    stageB(1, 0, kn1);
    asm volatile("s_waitcnt vmcnt(4)" ::: "memory");
    BAR();
    MMAQ(1, 1, bB);
    BAR();
  }
  // Drain remaining staged loads before retire (LDS-write vs next block).
  asm volatile("s_waitcnt vmcnt(0)" ::: "memory");

  const int erow = (lane >> 4) * 4, ecol = lane & 15;
  // fragment (ai,bj): row = m0 + (ai>>2)*128 + wm64 + (ai&3)*16,
  //                   col = n0 + (bj>>1)*128 + wn32 + (bj&1)*16
  if (!isqkv) {
#pragma unroll
    for (int ai = 0; ai < 8; ++ai) {
      const int gm0 = m0 + (ai >> 2) * 128 + wm64 + (ai & 3) * 16 + erow;
#pragma unroll
      for (int bj = 0; bj < 4; ++bj) {
        const int gn = n0 + (bj >> 1) * 128 + wn32 + (bj & 1) * 16 + ecol;
        const float bv = biasv[gn];
#pragma unroll
        for (int r = 0; r < 4; ++r)
          biasS[(size_t)(gm0 + r) * 2048 + gn] =
              __float2bfloat16((acc[ai][bj][r] + bv) * LOG2E);
      }
    }
  } else if (n0 < 2048) {
    const float sc = (n0 < 1024) ? 0.125f * LOG2E : 1.0f;
#pragma unroll
    for (int ai = 0; ai < 8; ++ai) {
      const int gm0 = m0 + (ai >> 2) * 128 + wm64 + (ai & 3) * 16 + erow;
#pragma unroll
      for (int bj = 0; bj < 4; ++bj) {
        const int gn = n0 + (bj >> 1) * 128 + wn32 + (bj & 1) * 16 + ecol;
        const float bv = biasv[gn];
#pragma unroll
        for (int r = 0; r < 4; ++r)
          QKb[(size_t)(gm0 + r) * 2048 + gn] =
              __float2bfloat16((acc[ai][bj][r] + bv) * sc);
      }
    }
  } else {
#pragma unroll
    for (int ai = 0; ai < 8; ++ai) {
      const int gm0 = m0 + (ai >> 2) * 128 + wm64 + (ai & 3) * 16 + erow;
      const int bb = gm0 >> 11;
      const int t = gm0 & 2047;
#pragma unroll
      for (int bj = 0; bj < 4; ++bj) {
        const int gn = n0 + (bj >> 1) * 128 + wn32 + (bj & 1) * 16 + ecol;
        const float bv = biasv[gn];
        const int d = gn - 2048;
        __align__(8) bf16 tmp[4];
#pragma unroll
        for (int r = 0; r < 4; ++r)
          tmp[r] = __float2bfloat16(acc[ai][bj][r] + bv);
        *(ushort4*)(Vt + ((size_t)(bb * 1024 + d)) * 2048 + t) =
            *(const ushort4*)tmp;
      }
    }
  }
#undef MMAQ
#undef LGKM0
#undef BAR
}

// ---------------------------------------------------------------------------
// Out projection: C(4096x1024) f32 = A(4096x1024)@(1024x1024)^T + bo.
// 128x64 tile, BK=64, dbuf, XCD-swizzled (2 n-blocks per XCD). 1D grid 512.
__global__ __launch_bounds__(256) void gemm_out(const bf16* __restrict__ A,
                                                const bf16* __restrict__ W,
                                                const float* __restrict__ biasv,
                                                float* __restrict__ C) {
  __shared__ __align__(16) bf16 As[2][128 * 64];  // 2 x 16 KB
  __shared__ __align__(16) bf16 Bs[2][64 * 64];   // 2 x 8 KB
  const int lin = blockIdx.x;
  const int xcd = lin & 7;
  const int kk = lin >> 3;  // 0..63
  const int m0 = (kk >> 1) * 128;
  const int n0 = (xcd * 2 + (kk & 1)) * 64;
  const int tid = threadIdx.x, lane = tid & 63, w = tid >> 6;
  const int wm = (w >> 1) * 64, wn = (w & 1) * 32;
  const int fr = lane & 15;
  const int ck = lane >> 4;

  f32x4 acc[4][2];
  const f32x4 fzero = {0.f, 0.f, 0.f, 0.f};
#pragma unroll
  for (int i = 0; i < 4; ++i)
#pragma unroll
    for (int j = 0; j < 2; ++j) acc[i][j] = fzero;

  auto stage = [&](int it, int buf) {
    const int k0 = it * 64;
#pragma unroll
    for (int is = 0; is < 4; ++is) {
      const int off = is * 4096 + w * 1024;
      const int row = (off >> 7) + (lane >> 3);
      const int sch = ((lane & 7) ^ (row & 7)) * 8;
      async_copy16(A + (size_t)(m0 + row) * 1024 + k0 + sch,
                   (char*)As[buf] + off);
      if (is < 2)
        async_copy16(W + (size_t)(n0 + row) * 1024 + k0 + sch,
                     (char*)Bs[buf] + off);
    }
  };

  stage(0, 0);
  __syncthreads();
  for (int it = 0; it < 16; ++it) {
    const int cur = it & 1;
    if (it + 1 < 16) stage(it + 1, cur ^ 1);
#pragma unroll
    for (int ks = 0; ks < 2; ++ks) {
      bf16x8 af[4], bfr[2];
      const int swk0 = (((ks * 4 + ck) ^ (fr & 7))) * 8;
#pragma unroll
      for (int i = 0; i < 4; ++i)
        af[i] = *(const bf16x8*)(As[cur] + (wm + i * 16 + fr) * 64 + swk0);
#pragma unroll
      for (int j = 0; j < 2; ++j)
        bfr[j] = *(const bf16x8*)(Bs[cur] + (wn + j * 16 + fr) * 64 + swk0);
#pragma unroll
      for (int i = 0; i < 4; ++i)
#pragma unroll
        for (int j = 0; j < 2; ++j)
          acc[i][j] = mfma16x16x32(af[i], bfr[j], acc[i][j]);
    }
    __syncthreads();
  }
  const int erow = (lane >> 4) * 4;
  const int ecol = lane & 15;
#pragma unroll
  for (int i = 0; i < 4; ++i) {
    const int gm0 = m0 + wm + i * 16 + erow;
#pragma unroll
    for (int j = 0; j < 2; ++j) {
      const int gn = n0 + wn + j * 16 + ecol;
      const float bv = biasv[gn];
#pragma unroll
      for (int r = 0; r < 4; ++r)
        C[(size_t)(gm0 + r) * 1024 + gn] = acc[i][j][r] + bv;
    }
  }
}

// ---------------------------------------------------------------------------
// Flash attention, S^T formulation, no-max softmax, key-split, TWO HEADS per
// block: one bias fetch serves both heads' S C-init. Proven R1 structure
// (2-barrier, single-buffered K/V) with ONE change: Ps uses the stride-64
// XOR chunk swizzle (verified R6/R7/R8) instead of stride-72 padding.
// Measured: stride-72 -> 3.15M LDS conflict cycles; XOR-64 -> 2.21M (same
// instruction count). Also LDS 50.7 -> 48 KB.
// 1D grid 512 = 16 qblk x 2 half x 8 head-pairs x 2 b.
__global__ __launch_bounds__(256) void flash_attn(
    const bf16* __restrict__ Qm, const bf16* __restrict__ Km,
    const bf16* __restrict__ Vtm, const bf16* __restrict__ biasS,
    float* __restrict__ Op0, float* __restrict__ Op1,
    float* __restrict__ lpart) {
  __shared__ __align__(16) bf16 Ks[2][64 * 64];   // per head, 16 KB
  __shared__ __align__(16) bf16 Vs[2][64 * 64];   // per head, 16 KB
  __shared__ __align__(16) bf16 Ps[4 * 32 * 64];  // per-wave P^T (swz), 16 KB
  const int lin = blockIdx.x;
  const int xcd = lin & 7;
  const int kk = lin >> 3;        // 0..63
  const int cl = kk & 1;
  const int r2 = kk >> 1;         // 0..31
  const int half = r2 & 1;
  const int q0 = (r2 >> 1) * 128;
  const int combo = xcd * 2 + cl; // 0..15
  const int hp = combo & 7;       // head pair
  const int b = combo >> 3;
  const int tid = threadIdx.x, lane = tid & 63, w = tid >> 6;
  const int ql = lane & 15, qk = lane >> 4;
  const int T = 2048, D = 1024;
  const int sw0 = (qk ^ (ql & 7)) * 8;
  const int sw1 = ((qk + 4) ^ (ql & 7)) * 8;
  const int qla7 = ql & 7;

  // Q B-frags for both heads: B[n=q][k=d], 2 q-subtiles x 2 k-steps
  bf16x8 qf[2][2][2];  // [head][qt][ks]
#pragma unroll
  for (int hh = 0; hh < 2; ++hh)
#pragma unroll
    for (int qt = 0; qt < 2; ++qt)
#pragma unroll
      for (int ks = 0; ks < 2; ++ks)
        qf[hh][qt][ks] = *(const bf16x8*)(
            Qm + (size_t)(b * T + q0 + w * 32 + qt * 16 + ql) * 2048 +
            (hp * 2 + hh) * 64 + ks * 32 + qk * 8);

  f32x4 acc[2][4][2];  // [head][dt][qt]
  const f32x4 fzero = {0.f, 0.f, 0.f, 0.f};
#pragma unroll
  for (int hh = 0; hh < 2; ++hh)
#pragma unroll
    for (int dt = 0; dt < 4; ++dt)
#pragma unroll
      for (int qt = 0; qt < 2; ++qt) acc[hh][dt][qt] = fzero;
  float lp[2][2] = {{0.f, 0.f}, {0.f, 0.f}};

  const bf16* kbase0 = Km + (size_t)(b * T) * 2048 + (hp * 2) * 64;
  const bf16* vbase0 = Vtm + (size_t)(b * D + hp * 2 * 64) * 2048;
  const bf16* bb0 = biasS + (size_t)(b * T + q0 + w * 32 + ql) * 2048 + qk * 4;
  bf16* pb = Ps + w * 2048;

  for (int j = 0; j < 16; ++j) {
    const int jj = half * 16 + j;  // global key-block
    __syncthreads();
#pragma unroll
    for (int hh = 0; hh < 2; ++hh)
#pragma unroll
      for (int is = 0; is < 2; ++is) {
        const int off = is * 4096 + w * 1024;
        const int row = (off >> 7) + (lane >> 3);
        const int sch = ((lane & 7) ^ (row & 7)) * 8;
        async_copy16(kbase0 + (size_t)(jj * 64 + row) * 2048 + hh * 64 + sch,
                     (char*)Ks[hh] + off);
        async_copy16(vbase0 + (size_t)(hh * 64 + row) * 2048 + jj * 64 + sch,
                     (char*)Vs[hh] + off);
      }
    // bias prefetch: ONE fetch for BOTH heads (overlaps staging drain)
    ushort4 bq[2][4];
#pragma unroll
    for (int qt = 0; qt < 2; ++qt)
#pragma unroll
      for (int jt = 0; jt < 4; ++jt)
        bq[qt][jt] = *(const ushort4*)(bb0 + (size_t)qt * 16 * 2048 + jj * 64 +
                                       jt * 16);
    __syncthreads();
#pragma unroll
    for (int hh = 0; hh < 2; ++hh) {
      const bf16* ksp = Ks[hh];
      const bf16* vsp = Vs[hh];
      // S^T tiles: rows=key, cols=q; bias as MFMA C-init (shared)
#pragma unroll
      for (int jt = 0; jt < 4; ++jt) {
        const bf16x8 kf0 = *(const bf16x8*)(ksp + (jt * 16 + ql) * 64 + sw0);
        const bf16x8 kf1 = *(const bf16x8*)(ksp + (jt * 16 + ql) * 64 + sw1);
        // P store: key-chunk (jt*2 + qk/2) XOR row&7, half-chunk by qk&1
        const int pch =
            (((jt * 2 + (qk >> 1)) ^ qla7) << 3) + ((qk & 1) << 2);
#pragma unroll
        for (int qt = 0; qt < 2; ++qt) {
          f32x4 c;
          c[0] = bfu2f(bq[qt][jt].x); c[1] = bfu2f(bq[qt][jt].y);
          c[2] = bfu2f(bq[qt][jt].z); c[3] = bfu2f(bq[qt][jt].w);
          c = mfma16x16x32(kf0, qf[hh][qt][0], c);
          c = mfma16x16x32(kf1, qf[hh][qt][1], c);
          __align__(8) bf16 t4[4];
#pragma unroll
          for (int r = 0; r < 4; ++r) {
            const float pv = __builtin_amdgcn_exp2f(c[r]);
            lp[hh][qt] += pv;
            t4[r] = __float2bfloat16(pv);
          }
          *(ushort4*)(pb + (qt * 16 + ql) * 64 + pch) = *(const ushort4*)t4;
        }
      }
      // O[q][d] += P.V^T ; V-frags shared across q-subtiles
      __builtin_amdgcn_s_setprio(1);
#pragma unroll
      for (int ks = 0; ks < 2; ++ks) {
        const int psw = (((ks * 4 + qk) ^ qla7) << 3);
        const bf16x8 pf0 = *(const bf16x8*)(pb + ql * 64 + psw);
        const bf16x8 pf1 = *(const bf16x8*)(pb + (16 + ql) * 64 + psw);
        const int sw = ks ? sw1 : sw0;
#pragma unroll
        for (int dt = 0; dt < 4; ++dt) {
          const bf16x8 vf = *(const bf16x8*)(vsp + (dt * 16 + ql) * 64 + sw);
          acc[hh][dt][0] = mfma16x16x32(pf0, vf, acc[hh][dt][0]);
          acc[hh][dt][1] = mfma16x16x32(pf1, vf, acc[hh][dt][1]);
        }
      }
      __builtin_amdgcn_s_setprio(0);
    }
  }
  // l partials: reduce across quads (lane's p-values all share q = ...+ql)
#pragma unroll
  for (int hh = 0; hh < 2; ++hh)
#pragma unroll
    for (int qt = 0; qt < 2; ++qt) {
      lp[hh][qt] += __shfl_xor(lp[hh][qt], 16);
      lp[hh][qt] += __shfl_xor(lp[hh][qt], 32);
    }
  if (qk == 0) {
#pragma unroll
    for (int hh = 0; hh < 2; ++hh)
#pragma unroll
      for (int qt = 0; qt < 2; ++qt)
        lpart[half * 65536 + (b * 16 + hp * 2 + hh) * 2048 + q0 + w * 32 +
              qt * 16 + ql] = lp[hh][qt];
  }
  float* Op = half ? Op1 : Op0;
#pragma unroll
  for (int hh = 0; hh < 2; ++hh)
#pragma unroll
    for (int qt = 0; qt < 2; ++qt)
#pragma unroll
      for (int r = 0; r < 4; ++r) {
        const size_t orow =
            (size_t)(b * T + q0 + w * 32 + qt * 16 + qk * 4 + r);
#pragma unroll
        for (int dt = 0; dt < 4; ++dt)
          Op[orow * 1024 + (hp * 2 + hh) * 64 + dt * 16 + ql] =
              acc[hh][dt][qt][r];
      }
}

// ---------------------------------------------------------------------------
// Combine key-half partials: AOut = bf16((O0+O1) / (l0+l1)). grid 4096 x 256.
__global__ __launch_bounds__(256) void combine(const float* __restrict__ O0,
                                               const float* __restrict__ O1,
                                               const float* __restrict__ lpart,
                                               bf16* __restrict__ AOut) {
  const int idx = blockIdx.x * 256 + threadIdx.x;  // 0..1048575
  const int row = idx >> 8;
  const int col = (idx & 255) * 4;
  const int b = row >> 11, q = row & 2047, h = col >> 6;
  const int li = (b * 16 + h) * 2048 + q;
  const float inv = __builtin_amdgcn_rcpf(lpart[li] + lpart[65536 + li]);
  const float4 a = *(const float4*)(O0 + (size_t)row * 1024 + col);
  const float4 c = *(const float4*)(O1 + (size_t)row * 1024 + col);
  __align__(8) bf16 t[4] = {
      __float2bfloat16((a.x + c.x) * inv), __float2bfloat16((a.y + c.y) * inv),
      __float2bfloat16((a.z + c.z) * inv), __float2bfloat16((a.w + c.w) * inv)};
  *(ushort4*)(AOut + (size_t)row * 1024 + col) = *(const ushort4*)t;
}

// ---------------------------------------------------------------------------
extern "C" void kernel_launch(void* const* d_in, const int* in_sizes, int n_in,
                              void* d_out, int out_size, void* d_ws,
                              size_t ws_size, hipStream_t stream) {
  (void)in_sizes; (void)n_in; (void)out_size; (void)ws_size;
  const float* Hx = (const float*)d_in[0];
  const float* Hf = (const float*)d_in[1];
  const float* Gm = (const float*)d_in[2];
  const float* Wg = (const float*)d_in[3];
  const float* bg = (const float*)d_in[4];
  const float* Wq = (const float*)d_in[5];
  const float* bq = (const float*)d_in[6];
  const float* Wk = (const float*)d_in[7];
  const float* bk = (const float*)d_in[8];
  const float* Wv = (const float*)d_in[9];
  const float* bv = (const float*)d_in[10];
  const float* Wo = (const float*)d_in[11];
  const float* bo = (const float*)d_in[12];
  float* out = (float*)d_out;

  char* p = (char*)d_ws;
  bf16* hcat = (bf16*)p;   p += (size_t)4096 * 2048 * 2;  // (B*T, 2D)
  bf16* QKb = (bf16*)p;    p += (size_t)4096 * 2048 * 2;  // (B*T, Q|K)
  bf16* Vtb = (bf16*)p;    p += (size_t)4096 * 1024 * 2;  // (B, D, T)
  bf16* biasS = (bf16*)p;  p += (size_t)4096 * 2048 * 2;  // (B*T, T) * log2e
  bf16* AOut = (bf16*)p;   p += (size_t)4096 * 1024 * 2;
  bf16* Wqkvb = (bf16*)p;  p += (size_t)3072 * 2048 * 2;  // (3N, K) packed
  bf16* Wob = (bf16*)p;    p += (size_t)1024 * 1024 * 2;
  bf16* Wgb = (bf16*)p;    p += (size_t)2048 * 256 * 2;
  bf16* Gmb = (bf16*)p;    p += (size_t)4096 * 256 * 2;
  float* qkvbias = (float*)p; p += (size_t)3072 * 4;
  float* Op1 = (float*)p;  p += (size_t)4096 * 1024 * 4;  // key-half-1 partial
  float* lpart = (float*)p; p += (size_t)2 * 65536 * 4;   // l partials
  float* Op0 = (float*)hcat;  // hcat is dead after gemm_qkv_bias; 16.8 MB fits

  pack_hx<<<dim3(32, 16, 2), 256, 0, stream>>>(Hx, hcat);
  pack_all<<<dim3(12803), 256, 0, stream>>>(Hf, Wq, Wk, Wv, Wo, Wg, Gm, bq, bk,
                                            bv, hcat, Wqkvb, Wob, Wgb, Gmb,
                                            qkvbias);
  // QKV projection + attention-bias GEMM, 256^2 8-phase, one dispatch
  gemm_qkv_bias<<<dim3(320), 512, 0, stream>>>(hcat, Wqkvb, qkvbias, Gmb,
                                               Wgb, bg, QKb, Vtb, biasS);
  // fused attention, key-split halves, 2 heads/block (bias shared, swz Ps)
  flash_attn<<<dim3(512), 256, 0, stream>>>(QKb, QKb + 1024, Vtb, biasS,
                                            Op0, Op1, lpart);
  // combine partials -> AOut bf16
  combine<<<dim3(4096), 256, 0, stream>>>(Op0, Op1, lpart, AOut);
  // output projection (fp32 out), XCD-swizzled
  gemm_out<<<dim3(512), 256, 0, stream>>>(AOut, Wob, bo, out);
}